// Round 8
// baseline (1194.173 us; speedup 1.0000x reference)
//
#include <hip/hip_runtime.h>
#include <math.h>

#define BB 1024   // batch
#define VV 256    // variables
#define KK 64     // categories
#define N0 8192   // input nodes
#define CC 32     // sum-node children
#define W  128    // batch chunk = B/8; chunk (blockIdx&7) pinned per XCD (perf heuristic only)

#define LOG2E 1.4426950408889634f
#define LN2   0.6931471805599453f

static __device__ __forceinline__ float fexp2(float x) { return __builtin_amdgcn_exp2f(x); }
static __device__ __forceinline__ float flog2(float x) { return __builtin_amdgcn_logf(x); }
static __device__ __forceinline__ float bf2f(unsigned short u) {
    union { unsigned int i; float f; } c; c.i = (unsigned int)u << 16; return c.f;
}
static __device__ __forceinline__ unsigned short f2bf(float f) {
    union { float f; unsigned int i; } c; c.f = f;
    unsigned int r = c.i + 0x7FFFu + ((c.i >> 16) & 1u);  // RNE
    return (unsigned short)(r >> 16);
}

// ---------------------------------------------------------------------------
// Manual grid barrier (plain launch, graph-capture safe). Hierarchical:
// per-chunk counters (128B-spaced) -> global 8-counter -> generation flip.
// Agent-scope atomics + __threadfence give cross-XCD visibility regardless of
// block->XCD mapping (G16-safe). Zeroed via hipMemsetAsync before launch.
// ---------------------------------------------------------------------------
struct GBar {
    unsigned int cnt[8 * 32];   // per-chunk arrival counters, 128B apart
    unsigned int gcnt;          // chunk-leader counter
    unsigned int pad[31];
    unsigned int gen;           // generation (monotone per barrier use)
};

static __device__ __forceinline__ void gbar(GBar* bar, int chunk, unsigned int per_chunk) {
    __syncthreads();
    __threadfence();   // release: drain + L2 writeback (agent scope)
    if (threadIdx.x == 0) {
        unsigned int g = __hip_atomic_load(&bar->gen, __ATOMIC_RELAXED, __HIP_MEMORY_SCOPE_AGENT);
        unsigned int a = __hip_atomic_fetch_add(&bar->cnt[chunk * 32], 1u,
                                                __ATOMIC_ACQ_REL, __HIP_MEMORY_SCOPE_AGENT);
        if (a + 1 == per_chunk) {
            __hip_atomic_store(&bar->cnt[chunk * 32], 0u, __ATOMIC_RELAXED, __HIP_MEMORY_SCOPE_AGENT);
            unsigned int ag = __hip_atomic_fetch_add(&bar->gcnt, 1u,
                                                     __ATOMIC_ACQ_REL, __HIP_MEMORY_SCOPE_AGENT);
            if (ag + 1 == 8u) {
                __hip_atomic_store(&bar->gcnt, 0u, __ATOMIC_RELAXED, __HIP_MEMORY_SCOPE_AGENT);
                __hip_atomic_store(&bar->gen, g + 1u, __ATOMIC_RELEASE, __HIP_MEMORY_SCOPE_AGENT);
            }
        }
        while (__hip_atomic_load(&bar->gen, __ATOMIC_ACQUIRE, __HIP_MEMORY_SCOPE_AGENT) == g) {
            __builtin_amdgcn_s_sleep(2);
        }
    }
    __syncthreads();
    __threadfence();   // acquire: invalidate stale L1/L2 on every CU
}

// ---------------------------------------------------------------------------
// prod phase: 8 elements per group (8 subs x 32 lanes x 4 cols), grid-stride.
// em[e][b..] = nm[p0][b..] + nm[p1][b..]  (log2 domain), bf16 store.
// ---------------------------------------------------------------------------
static __device__ __forceinline__ void prod_phase(const float* __restrict__ nm,
                                                  const int* __restrict__ pids,
                                                  unsigned short* __restrict__ em,
                                                  int E, int grp, int ngrp,
                                                  int sub, int lane, int chunk) {
    int b = chunk * W + lane * 4;
    for (int g = grp; g < (E >> 3); g += ngrp) {
        int e = g * 8 + sub;
        int p0 = pids[e * 2 + 0];
        int p1 = pids[e * 2 + 1];
        const float4 a = *(const float4*)(nm + (size_t)p0 * BB + b);
        const float4 c = *(const float4*)(nm + (size_t)p1 * BB + b);
        ushort4 o;
        o.x = f2bf(a.x + c.x); o.y = f2bf(a.y + c.y);
        o.z = f2bf(a.z + c.z); o.w = f2bf(a.w + c.w);
        *(ushort4*)(em + (size_t)e * BB + b) = o;
    }
}

// ---------------------------------------------------------------------------
// sum phase: 8 sum nodes per group, grid-stride. Children in 2 groups of 16
// + online combine. em bf16 in, nm fp32 out.
// ---------------------------------------------------------------------------
static __device__ __forceinline__ void sum_phase(const unsigned short* __restrict__ em,
                                                 const int* __restrict__ cids,
                                                 const float* __restrict__ w,
                                                 float* __restrict__ out,
                                                 int S, int grp, int ngrp,
                                                 int sub, int lane, int chunk,
                                                 float (*slw)[CC], int (*scid)[CC]) {
    int b = chunk * W + lane * 4;
    for (int g = grp; g < (S >> 3); g += ngrp) {
        int s = g * 8 + sub;
        {
            float lw = w[s * CC + lane];
            float m = lw;
            #pragma unroll
            for (int d = 16; d; d >>= 1) m = fmaxf(m, __shfl_xor(m, d, 32));
            float su0 = __expf(lw - m);
            #pragma unroll
            for (int d = 16; d; d >>= 1) su0 += __shfl_xor(su0, d, 32);
            slw[sub][lane] = (lw - m) * LOG2E - flog2(su0);
            scid[sub][lane] = cids[s * CC + lane] - 1;
        }
        __syncthreads();
        float4 mx, su;
        #pragma unroll
        for (int grp2 = 0; grp2 < 2; ++grp2) {
            float4 v[16];
            float4 gmx = {-INFINITY, -INFINITY, -INFINITY, -INFINITY};
            #pragma unroll
            for (int c = 0; c < 16; ++c) {
                int cc = grp2 * 16 + c;
                ushort4 t4 = *(const ushort4*)(em + (size_t)scid[sub][cc] * BB + b);
                float lw = slw[sub][cc];
                float4 t;
                t.x = bf2f(t4.x) + lw; t.y = bf2f(t4.y) + lw;
                t.z = bf2f(t4.z) + lw; t.w = bf2f(t4.w) + lw;
                v[c] = t;
                gmx.x = fmaxf(gmx.x, t.x); gmx.y = fmaxf(gmx.y, t.y);
                gmx.z = fmaxf(gmx.z, t.z); gmx.w = fmaxf(gmx.w, t.w);
            }
            float4 gsu = {0.f, 0.f, 0.f, 0.f};
            #pragma unroll
            for (int c = 0; c < 16; ++c) {
                gsu.x += fexp2(v[c].x - gmx.x);
                gsu.y += fexp2(v[c].y - gmx.y);
                gsu.z += fexp2(v[c].z - gmx.z);
                gsu.w += fexp2(v[c].w - gmx.w);
            }
            if (grp2 == 0) {
                mx = gmx; su = gsu;
            } else {
                float4 nmx;
                nmx.x = fmaxf(mx.x, gmx.x); nmx.y = fmaxf(mx.y, gmx.y);
                nmx.z = fmaxf(mx.z, gmx.z); nmx.w = fmaxf(mx.w, gmx.w);
                su.x = su.x * fexp2(mx.x - nmx.x) + gsu.x * fexp2(gmx.x - nmx.x);
                su.y = su.y * fexp2(mx.y - nmx.y) + gsu.y * fexp2(gmx.y - nmx.y);
                su.z = su.z * fexp2(mx.z - nmx.z) + gsu.z * fexp2(gmx.z - nmx.z);
                su.w = su.w * fexp2(mx.w - nmx.w) + gsu.w * fexp2(gmx.w - nmx.w);
                mx = nmx;
            }
        }
        float4 o;
        o.x = mx.x + flog2(su.x);
        o.y = mx.y + flog2(su.y);
        o.z = mx.z + flog2(su.z);
        o.w = mx.w + flog2(su.w);
        *(float4*)(out + (size_t)s * BB + b) = o;
        __syncthreads();
    }
}

// ---------------------------------------------------------------------------
// mega kernel: whole net in one plain launch; manual grid barriers between
// phases. Grid is any multiple of 8 (grid-stride loops); host guarantees
// co-residency via the occupancy API.
// ---------------------------------------------------------------------------
__global__ void __launch_bounds__(256, 4) k_mega(
        const int* __restrict__ x, const float* __restrict__ logits,
        const float* __restrict__ w1, const float* __restrict__ w2,
        const float* __restrict__ w3, const float* __restrict__ w4,
        const int* __restrict__ pids1, const int* __restrict__ pids2,
        const int* __restrict__ pids3, const int* __restrict__ pids4,
        const int* __restrict__ cids1, const int* __restrict__ cids2,
        const int* __restrict__ cids3, const int* __restrict__ cids4,
        float* __restrict__ nm, unsigned short* __restrict__ em,
        float* __restrict__ lp, int* __restrict__ xt,
        GBar* __restrict__ bar,
        float* __restrict__ out) {
    int bid = blockIdx.x;
    int tid = threadIdx.x;
    int G = gridDim.x;
    int ngrp = G >> 3;
    unsigned int per_chunk = (unsigned int)ngrp;
    int chunk = bid & 7;
    int grp = bid >> 3;
    int sub = tid >> 5;
    int lane = tid & 31;
    __shared__ float slw[8][CC];
    __shared__ int scid[8][CC];

    // ---- phase A: transpose x -> xt; log2-softmax rows -> lp
    for (int idx = bid * 256 + tid; idx < VV * BB; idx += G * 256) {
        int v = idx >> 10, b = idx & (BB - 1);
        xt[idx] = x[b * VV + v];
    }
    {
        int k = tid & 63;
        int wave0 = (bid * 256 + tid) >> 6;
        for (int r = wave0; r < N0; r += G * 4) {
            float l = logits[(size_t)r * KK + k];
            float m = l;
            #pragma unroll
            for (int d = 32; d; d >>= 1) m = fmaxf(m, __shfl_xor(m, d));
            float s = __expf(l - m);
            #pragma unroll
            for (int d = 32; d; d >>= 1) s += __shfl_xor(s, d);
            lp[(size_t)r * KK + k] = (l - m) * LOG2E - flog2(s);
        }
    }
    gbar(bar, chunk, per_chunk);

    // ---- phase B: input gather -> nm rows 1..8192 (cols of this chunk)
    {
        int half = tid >> 7;
        int t = tid & 127;
        int b = chunk * W + t;
        for (int g8 = grp * 2 + half; g8 < (N0 >> 3); g8 += ngrp * 2) {
            int i0 = g8 * 8;
            int v = i0 >> 5;                 // nodes i0..i0+7 share the variable
            int xv = xt[v * BB + b];
            #pragma unroll
            for (int j = 0; j < 8; ++j) {
                int i = i0 + j;
                nm[(size_t)(1 + i) * BB + b] = lp[(size_t)i * KK + xv];
            }
        }
    }
    gbar(bar, chunk, per_chunk);

    // ---- layer 1: E=8192 -> S=4096 (nm rows 8193..12288)
    prod_phase(nm, pids1, em, 8192, grp, ngrp, sub, lane, chunk);
    gbar(bar, chunk, per_chunk);
    sum_phase(em, cids1, w1, nm + (size_t)8193 * BB, 4096, grp, ngrp, sub, lane, chunk, slw, scid);
    gbar(bar, chunk, per_chunk);
    // ---- layer 2: E=4096 -> S=2048 (nm rows 12289..14336)
    prod_phase(nm, pids2, em, 4096, grp, ngrp, sub, lane, chunk);
    gbar(bar, chunk, per_chunk);
    sum_phase(em, cids2, w2, nm + (size_t)12289 * BB, 2048, grp, ngrp, sub, lane, chunk, slw, scid);
    gbar(bar, chunk, per_chunk);
    // ---- layer 3: E=2048 -> S=1024 (nm rows 14337..15360)
    prod_phase(nm, pids3, em, 2048, grp, ngrp, sub, lane, chunk);
    gbar(bar, chunk, per_chunk);
    sum_phase(em, cids3, w3, nm + (size_t)14337 * BB, 1024, grp, ngrp, sub, lane, chunk, slw, scid);
    gbar(bar, chunk, per_chunk);

    // ---- root: prod4+sum4 fused; only the 32 referenced elements computed.
    if (grp == 0) {
        if (tid < CC) {
            float lw = w4[tid];
            float m = lw;
            #pragma unroll
            for (int d = 16; d; d >>= 1) m = fmaxf(m, __shfl_xor(m, d, 32));
            float su = __expf(lw - m);
            #pragma unroll
            for (int d = 16; d; d >>= 1) su += __shfl_xor(su, d, 32);
            slw[0][tid] = (lw - m) * LOG2E - flog2(su);
            int e = cids4[tid] - 1;
            scid[0][tid] = pids4[e * 2 + 0];
            scid[1][tid] = pids4[e * 2 + 1];
        }
        __syncthreads();
        if (tid < W) {
            int b = chunk * W + tid;
            float v[CC];
            float mx = -INFINITY;
            #pragma unroll
            for (int c = 0; c < CC; ++c) {
                v[c] = nm[(size_t)scid[0][c] * BB + b] + nm[(size_t)scid[1][c] * BB + b] + slw[0][c];
                mx = fmaxf(mx, v[c]);
            }
            float su = 0.f;
            #pragma unroll
            for (int c = 0; c < CC; ++c) su += fexp2(v[c] - mx);
            out[b] = (mx + flog2(su)) * LN2;
        }
    }
}

// ---------------------------------------------------------------------------
// Launch: one memsetAsync (barrier init) + one plain kernel launch.
// Grid computed from the occupancy API (host-side, capture-safe) so all
// blocks are guaranteed co-resident; loops are grid-stride so any multiple
// of 8 is correct.
// ---------------------------------------------------------------------------
extern "C" void kernel_launch(void* const* d_in, const int* in_sizes, int n_in,
                              void* d_out, int out_size, void* d_ws, size_t ws_size,
                              hipStream_t stream) {
    const int*   x         = (const int*)  d_in[0];
    const float* in_logits = (const float*)d_in[1];
    const float* w1        = (const float*)d_in[2];
    const float* w2        = (const float*)d_in[3];
    const float* w3        = (const float*)d_in[4];
    const float* w4        = (const float*)d_in[5];
    const int*   pids1     = (const int*)  d_in[6];
    const int*   pids2     = (const int*)  d_in[7];
    const int*   pids3     = (const int*)  d_in[8];
    const int*   pids4     = (const int*)  d_in[9];
    const int*   cids1     = (const int*)  d_in[10];
    const int*   cids2     = (const int*)  d_in[11];
    const int*   cids3     = (const int*)  d_in[12];
    const int*   cids4     = (const int*)  d_in[13];
    float* out = (float*)d_out;

    float*          nm = (float*)d_ws;                               // 15361*1024 f32
    unsigned short* em = (unsigned short*)(nm + (size_t)15361 * BB); //  8192*1024 bf16
    float*          lp = (float*)(em + (size_t)8192 * BB);           //  8192*64 f32
    int*            xt = (int*)(lp + (size_t)N0 * KK);               //   256*1024 i32
    GBar*           bar = (GBar*)(xt + (size_t)VV * BB);

    int bpc = 0;
    hipOccupancyMaxActiveBlocksPerMultiprocessor(&bpc, (const void*)k_mega, 256, 0);
    int ncu = 0;
    hipDeviceGetAttribute(&ncu, hipDeviceAttributeMultiprocessorCount, 0);
    long long cap = (long long)bpc * (long long)ncu;
    int grid = (cap > 1024) ? 1024 : (int)cap;
    grid &= ~7;
    if (grid < 8) grid = 8;

    hipMemsetAsync(bar, 0, sizeof(GBar), stream);
    k_mega<<<grid, 256, 0, stream>>>(x, in_logits, w1, w2, w3, w4,
                                     pids1, pids2, pids3, pids4,
                                     cids1, cids2, cids3, cids4,
                                     nm, em, lp, xt, bar, out);
}

// Round 9
// 411.066 us; speedup vs baseline: 2.9051x; 2.9051x over previous
//
#include <hip/hip_runtime.h>
#include <math.h>

#define BB 1024   // batch
#define VV 256    // variables
#define KK 64     // categories
#define N0 8192   // input nodes
#define CC 32     // sum-node children
#define W  128    // batch chunk = B/8; chunk (blockIdx&7) pinned per XCD (perf heuristic only)

#define LOG2E 1.4426950408889634f
#define LN2   0.6931471805599453f

static __device__ __forceinline__ float fexp2(float x) { return __builtin_amdgcn_exp2f(x); }
static __device__ __forceinline__ float flog2(float x) { return __builtin_amdgcn_logf(x); }
static __device__ __forceinline__ float bf2f(unsigned short u) {
    union { unsigned int i; float f; } c; c.i = (unsigned int)u << 16; return c.f;
}
static __device__ __forceinline__ unsigned short f2bf(float f) {
    union { float f; unsigned int i; } c; c.f = f;
    unsigned int r = c.i + 0x7FFFu + ((c.i >> 16) & 1u);  // RNE
    return (unsigned short)(r >> 16);
}

// ---------------------------------------------------------------------------
// Manual grid barrier, R9 fix: the R8 version spun on an ACQUIRE load, which
// emits buffer_inv (full L1+L2 invalidate) PER POLL on gfx950 -> continuous
// L2 destruction (R8: 2.4% VALUBusy, 400MB FETCH). Now: exactly ONE release
// (arrival fetch_add) and ONE acquire (single confirming load after the
// relaxed spin exits) per block per barrier. Relaxed agent loads don't
// invalidate. Hierarchical arrival: 128 atomics/chunk line, 8 chunk leaders.
// ---------------------------------------------------------------------------
struct GBar {
    unsigned int cnt[8 * 32];   // per-chunk arrival counters, 128B apart
    unsigned int gcnt;          // chunk-leader counter
    unsigned int pad[31];
    unsigned int gen;           // generation (monotone per barrier use)
};

static __device__ __forceinline__ void gbar(GBar* bar, int chunk, unsigned int per_chunk) {
    __syncthreads();   // drains this block's vmcnt; orders all its waves' stores
    if (threadIdx.x == 0) {
        unsigned int g = __hip_atomic_load(&bar->gen, __ATOMIC_RELAXED, __HIP_MEMORY_SCOPE_AGENT);
        // RELEASE: single buffer_wbl2 pushing this XCD's dirty lines to the
        // coherence point, then the arrival increment.
        unsigned int a = __hip_atomic_fetch_add(&bar->cnt[chunk * 32], 1u,
                                                __ATOMIC_RELEASE, __HIP_MEMORY_SCOPE_AGENT);
        if (a + 1 == per_chunk) {
            __hip_atomic_store(&bar->cnt[chunk * 32], 0u, __ATOMIC_RELAXED, __HIP_MEMORY_SCOPE_AGENT);
            unsigned int ag = __hip_atomic_fetch_add(&bar->gcnt, 1u,
                                                     __ATOMIC_ACQ_REL, __HIP_MEMORY_SCOPE_AGENT);
            if (ag + 1 == 8u) {
                __hip_atomic_store(&bar->gcnt, 0u, __ATOMIC_RELAXED, __HIP_MEMORY_SCOPE_AGENT);
                __hip_atomic_store(&bar->gen, g + 1u, __ATOMIC_RELEASE, __HIP_MEMORY_SCOPE_AGENT);
            }
        }
        // RELAXED spin: no cache invalidation while waiting.
        while (__hip_atomic_load(&bar->gen, __ATOMIC_RELAXED, __HIP_MEMORY_SCOPE_AGENT) == g) {
            __builtin_amdgcn_s_sleep(4);
        }
        // ACQUIRE: single buffer_inv so this CU/XCD sees remote writes.
        (void)__hip_atomic_load(&bar->gen, __ATOMIC_ACQUIRE, __HIP_MEMORY_SCOPE_AGENT);
    }
    __syncthreads();
}

// ---------------------------------------------------------------------------
// prod phase: 8 elements per group (8 subs x 32 lanes x 4 cols), grid-stride.
// em[e][b..] = nm[p0][b..] + nm[p1][b..]  (log2 domain), bf16 store.
// ---------------------------------------------------------------------------
static __device__ __forceinline__ void prod_phase(const float* __restrict__ nm,
                                                  const int* __restrict__ pids,
                                                  unsigned short* __restrict__ em,
                                                  int E, int grp, int ngrp,
                                                  int sub, int lane, int chunk) {
    int b = chunk * W + lane * 4;
    for (int g = grp; g < (E >> 3); g += ngrp) {
        int e = g * 8 + sub;
        int p0 = pids[e * 2 + 0];
        int p1 = pids[e * 2 + 1];
        const float4 a = *(const float4*)(nm + (size_t)p0 * BB + b);
        const float4 c = *(const float4*)(nm + (size_t)p1 * BB + b);
        ushort4 o;
        o.x = f2bf(a.x + c.x); o.y = f2bf(a.y + c.y);
        o.z = f2bf(a.z + c.z); o.w = f2bf(a.w + c.w);
        *(ushort4*)(em + (size_t)e * BB + b) = o;
    }
}

// ---------------------------------------------------------------------------
// sum phase: 8 sum nodes per group, grid-stride. Children in 2 groups of 16
// + online combine. em bf16 in, nm fp32 out.
// ---------------------------------------------------------------------------
static __device__ __forceinline__ void sum_phase(const unsigned short* __restrict__ em,
                                                 const int* __restrict__ cids,
                                                 const float* __restrict__ w,
                                                 float* __restrict__ out,
                                                 int S, int grp, int ngrp,
                                                 int sub, int lane, int chunk,
                                                 float (*slw)[CC], int (*scid)[CC]) {
    int b = chunk * W + lane * 4;
    for (int g = grp; g < (S >> 3); g += ngrp) {
        int s = g * 8 + sub;
        {
            float lw = w[s * CC + lane];
            float m = lw;
            #pragma unroll
            for (int d = 16; d; d >>= 1) m = fmaxf(m, __shfl_xor(m, d, 32));
            float su0 = __expf(lw - m);
            #pragma unroll
            for (int d = 16; d; d >>= 1) su0 += __shfl_xor(su0, d, 32);
            slw[sub][lane] = (lw - m) * LOG2E - flog2(su0);
            scid[sub][lane] = cids[s * CC + lane] - 1;
        }
        __syncthreads();
        float4 mx, su;
        #pragma unroll
        for (int grp2 = 0; grp2 < 2; ++grp2) {
            float4 v[16];
            float4 gmx = {-INFINITY, -INFINITY, -INFINITY, -INFINITY};
            #pragma unroll
            for (int c = 0; c < 16; ++c) {
                int cc = grp2 * 16 + c;
                ushort4 t4 = *(const ushort4*)(em + (size_t)scid[sub][cc] * BB + b);
                float lw = slw[sub][cc];
                float4 t;
                t.x = bf2f(t4.x) + lw; t.y = bf2f(t4.y) + lw;
                t.z = bf2f(t4.z) + lw; t.w = bf2f(t4.w) + lw;
                v[c] = t;
                gmx.x = fmaxf(gmx.x, t.x); gmx.y = fmaxf(gmx.y, t.y);
                gmx.z = fmaxf(gmx.z, t.z); gmx.w = fmaxf(gmx.w, t.w);
            }
            float4 gsu = {0.f, 0.f, 0.f, 0.f};
            #pragma unroll
            for (int c = 0; c < 16; ++c) {
                gsu.x += fexp2(v[c].x - gmx.x);
                gsu.y += fexp2(v[c].y - gmx.y);
                gsu.z += fexp2(v[c].z - gmx.z);
                gsu.w += fexp2(v[c].w - gmx.w);
            }
            if (grp2 == 0) {
                mx = gmx; su = gsu;
            } else {
                float4 nmx;
                nmx.x = fmaxf(mx.x, gmx.x); nmx.y = fmaxf(mx.y, gmx.y);
                nmx.z = fmaxf(mx.z, gmx.z); nmx.w = fmaxf(mx.w, gmx.w);
                su.x = su.x * fexp2(mx.x - nmx.x) + gsu.x * fexp2(gmx.x - nmx.x);
                su.y = su.y * fexp2(mx.y - nmx.y) + gsu.y * fexp2(gmx.y - nmx.y);
                su.z = su.z * fexp2(mx.z - nmx.z) + gsu.z * fexp2(gmx.z - nmx.z);
                su.w = su.w * fexp2(mx.w - nmx.w) + gsu.w * fexp2(gmx.w - nmx.w);
                mx = nmx;
            }
        }
        float4 o;
        o.x = mx.x + flog2(su.x);
        o.y = mx.y + flog2(su.y);
        o.z = mx.z + flog2(su.z);
        o.w = mx.w + flog2(su.w);
        *(float4*)(out + (size_t)s * BB + b) = o;
        __syncthreads();
    }
}

// ---------------------------------------------------------------------------
// mega kernel: whole net in one plain launch; manual grid barriers between
// phases. Grid is any multiple of 8 (grid-stride loops); host guarantees
// co-residency via the occupancy API.
// ---------------------------------------------------------------------------
__global__ void __launch_bounds__(256, 4) k_mega(
        const int* __restrict__ x, const float* __restrict__ logits,
        const float* __restrict__ w1, const float* __restrict__ w2,
        const float* __restrict__ w3, const float* __restrict__ w4,
        const int* __restrict__ pids1, const int* __restrict__ pids2,
        const int* __restrict__ pids3, const int* __restrict__ pids4,
        const int* __restrict__ cids1, const int* __restrict__ cids2,
        const int* __restrict__ cids3, const int* __restrict__ cids4,
        float* __restrict__ nm, unsigned short* __restrict__ em,
        float* __restrict__ lp, int* __restrict__ xt,
        GBar* __restrict__ bar,
        float* __restrict__ out) {
    int bid = blockIdx.x;
    int tid = threadIdx.x;
    int G = gridDim.x;
    int ngrp = G >> 3;
    unsigned int per_chunk = (unsigned int)ngrp;
    int chunk = bid & 7;
    int grp = bid >> 3;
    int sub = tid >> 5;
    int lane = tid & 31;
    __shared__ float slw[8][CC];
    __shared__ int scid[8][CC];

    // ---- phase A: transpose x -> xt; log2-softmax rows -> lp
    for (int idx = bid * 256 + tid; idx < VV * BB; idx += G * 256) {
        int v = idx >> 10, b = idx & (BB - 1);
        xt[idx] = x[b * VV + v];
    }
    {
        int k = tid & 63;
        int wave0 = (bid * 256 + tid) >> 6;
        for (int r = wave0; r < N0; r += G * 4) {
            float l = logits[(size_t)r * KK + k];
            float m = l;
            #pragma unroll
            for (int d = 32; d; d >>= 1) m = fmaxf(m, __shfl_xor(m, d));
            float s = __expf(l - m);
            #pragma unroll
            for (int d = 32; d; d >>= 1) s += __shfl_xor(s, d);
            lp[(size_t)r * KK + k] = (l - m) * LOG2E - flog2(s);
        }
    }
    gbar(bar, chunk, per_chunk);

    // ---- phase B: input gather -> nm rows 1..8192 (cols of this chunk)
    {
        int half = tid >> 7;
        int t = tid & 127;
        int b = chunk * W + t;
        for (int g8 = grp * 2 + half; g8 < (N0 >> 3); g8 += ngrp * 2) {
            int i0 = g8 * 8;
            int v = i0 >> 5;                 // nodes i0..i0+7 share the variable
            int xv = xt[v * BB + b];
            #pragma unroll
            for (int j = 0; j < 8; ++j) {
                int i = i0 + j;
                nm[(size_t)(1 + i) * BB + b] = lp[(size_t)i * KK + xv];
            }
        }
    }
    gbar(bar, chunk, per_chunk);

    // ---- layer 1: E=8192 -> S=4096 (nm rows 8193..12288)
    prod_phase(nm, pids1, em, 8192, grp, ngrp, sub, lane, chunk);
    gbar(bar, chunk, per_chunk);
    sum_phase(em, cids1, w1, nm + (size_t)8193 * BB, 4096, grp, ngrp, sub, lane, chunk, slw, scid);
    gbar(bar, chunk, per_chunk);
    // ---- layer 2: E=4096 -> S=2048 (nm rows 12289..14336)
    prod_phase(nm, pids2, em, 4096, grp, ngrp, sub, lane, chunk);
    gbar(bar, chunk, per_chunk);
    sum_phase(em, cids2, w2, nm + (size_t)12289 * BB, 2048, grp, ngrp, sub, lane, chunk, slw, scid);
    gbar(bar, chunk, per_chunk);
    // ---- layer 3: E=2048 -> S=1024 (nm rows 14337..15360)
    prod_phase(nm, pids3, em, 2048, grp, ngrp, sub, lane, chunk);
    gbar(bar, chunk, per_chunk);
    sum_phase(em, cids3, w3, nm + (size_t)14337 * BB, 1024, grp, ngrp, sub, lane, chunk, slw, scid);
    gbar(bar, chunk, per_chunk);

    // ---- root: prod4+sum4 fused; only the 32 referenced elements computed.
    if (grp == 0) {
        if (tid < CC) {
            float lw = w4[tid];
            float m = lw;
            #pragma unroll
            for (int d = 16; d; d >>= 1) m = fmaxf(m, __shfl_xor(m, d, 32));
            float su = __expf(lw - m);
            #pragma unroll
            for (int d = 16; d; d >>= 1) su += __shfl_xor(su, d, 32);
            slw[0][tid] = (lw - m) * LOG2E - flog2(su);
            int e = cids4[tid] - 1;
            scid[0][tid] = pids4[e * 2 + 0];
            scid[1][tid] = pids4[e * 2 + 1];
        }
        __syncthreads();
        if (tid < W) {
            int b = chunk * W + tid;
            float v[CC];
            float mx = -INFINITY;
            #pragma unroll
            for (int c = 0; c < CC; ++c) {
                v[c] = nm[(size_t)scid[0][c] * BB + b] + nm[(size_t)scid[1][c] * BB + b] + slw[0][c];
                mx = fmaxf(mx, v[c]);
            }
            float su = 0.f;
            #pragma unroll
            for (int c = 0; c < CC; ++c) su += fexp2(v[c] - mx);
            out[b] = (mx + flog2(su)) * LN2;
        }
    }
}

// ---------------------------------------------------------------------------
// Launch: one memsetAsync (barrier init) + one plain kernel launch.
// Grid from the occupancy API (host-side, capture-safe) so all blocks are
// co-resident; loops are grid-stride so any multiple of 8 is correct.
// ---------------------------------------------------------------------------
extern "C" void kernel_launch(void* const* d_in, const int* in_sizes, int n_in,
                              void* d_out, int out_size, void* d_ws, size_t ws_size,
                              hipStream_t stream) {
    const int*   x         = (const int*)  d_in[0];
    const float* in_logits = (const float*)d_in[1];
    const float* w1        = (const float*)d_in[2];
    const float* w2        = (const float*)d_in[3];
    const float* w3        = (const float*)d_in[4];
    const float* w4        = (const float*)d_in[5];
    const int*   pids1     = (const int*)  d_in[6];
    const int*   pids2     = (const int*)  d_in[7];
    const int*   pids3     = (const int*)  d_in[8];
    const int*   pids4     = (const int*)  d_in[9];
    const int*   cids1     = (const int*)  d_in[10];
    const int*   cids2     = (const int*)  d_in[11];
    const int*   cids3     = (const int*)  d_in[12];
    const int*   cids4     = (const int*)  d_in[13];
    float* out = (float*)d_out;

    float*          nm = (float*)d_ws;                               // 15361*1024 f32
    unsigned short* em = (unsigned short*)(nm + (size_t)15361 * BB); //  8192*1024 bf16
    float*          lp = (float*)(em + (size_t)8192 * BB);           //  8192*64 f32
    int*            xt = (int*)(lp + (size_t)N0 * KK);               //   256*1024 i32
    GBar*           bar = (GBar*)(xt + (size_t)VV * BB);

    int bpc = 0;
    hipOccupancyMaxActiveBlocksPerMultiprocessor(&bpc, (const void*)k_mega, 256, 0);
    int ncu = 0;
    hipDeviceGetAttribute(&ncu, hipDeviceAttributeMultiprocessorCount, 0);
    long long cap = (long long)bpc * (long long)ncu;
    int grid = (cap > 1024) ? 1024 : (int)cap;
    grid &= ~7;
    if (grid < 8) grid = 8;

    hipMemsetAsync(bar, 0, sizeof(GBar), stream);
    k_mega<<<grid, 256, 0, stream>>>(x, in_logits, w1, w2, w3, w4,
                                     pids1, pids2, pids3, pids4,
                                     cids1, cids2, cids3, cids4,
                                     nm, em, lp, xt, bar, out);
}

// Round 10
// 167.912 us; speedup vs baseline: 7.1119x; 2.4481x over previous
//
#include <hip/hip_runtime.h>
#include <math.h>

#define BB 1024   // batch
#define VV 256    // variables
#define KK 64     // categories
#define N0 8192   // input nodes
#define CC 32     // sum-node children
#define W  128    // batch chunk = B/8; chunk (blockIdx&7) pinned per XCD (perf heuristic)

#define LOG2E 1.4426950408889634f
#define LN2   0.6931471805599453f

static __device__ __forceinline__ float fexp2(float x) { return __builtin_amdgcn_exp2f(x); }
static __device__ __forceinline__ float flog2(float x) { return __builtin_amdgcn_logf(x); }
static __device__ __forceinline__ float bf2f(unsigned short u) {
    union { unsigned int i; float f; } c; c.i = (unsigned int)u << 16; return c.f;
}
static __device__ __forceinline__ unsigned short f2bf(float f) {
    union { float f; unsigned int i; } c; c.f = f;
    unsigned int r = c.i + 0x7FFFu + ((c.i >> 16) & 1u);  // RNE
    return (unsigned short)(r >> 16);
}

// ---------------------------------------------------------------------------
// prep: blocks 0..1023 transpose x [B,V] -> xt [V,B]; blocks 1024..3071 do
// log2-softmax rows of in_logits -> lp (bf16), 4 rows/block (1 wave each).
// ---------------------------------------------------------------------------
__global__ void __launch_bounds__(256) k_prep(const int* __restrict__ x,
                                              const float* __restrict__ logits,
                                              int* __restrict__ xt,
                                              unsigned short* __restrict__ lp) {
    int bid = blockIdx.x;
    int tid = threadIdx.x;
    if (bid < 1024) {
        int idx = bid * 256 + tid;       // over V*B
        int v = idx >> 10, b = idx & (BB - 1);
        xt[idx] = x[b * VV + v];
    } else {
        int row = (bid - 1024) * 4 + (tid >> 6);
        int k = tid & 63;
        float l = logits[(size_t)row * KK + k];
        float m = l;
        #pragma unroll
        for (int d = 32; d; d >>= 1) m = fmaxf(m, __shfl_xor(m, d));
        float s = __expf(l - m);
        #pragma unroll
        for (int d = 32; d; d >>= 1) s += __shfl_xor(s, d);
        lp[(size_t)row * KK + k] = f2bf((l - m) * LOG2E - flog2(s));  // log2, bf16
    }
}

// ---------------------------------------------------------------------------
// input gather: block g -> chunk (g&7); 8 input nodes per block, 1 col/thread.
// nm[(1+i)*B + b] = lp[i][ xt[var(i)*B + b] ]   (bf16 passthrough)
// ---------------------------------------------------------------------------
__global__ void __launch_bounds__(W) k_input_gather(const unsigned short* __restrict__ lp,
                                                    const int* __restrict__ xt,
                                                    unsigned short* __restrict__ nm) {
    int g = blockIdx.x;
    int chunk = g & 7;
    int i0 = (g >> 3) * 8;
    int b = chunk * W + threadIdx.x;
    int v = i0 >> 5;                 // same variable for all 8 nodes
    int xv = xt[v * BB + b];
    #pragma unroll
    for (int j = 0; j < 8; ++j) {
        int i = i0 + j;
        nm[(size_t)(1 + i) * BB + b] = lp[(size_t)i * KK + xv];
    }
}

// ---------------------------------------------------------------------------
// product layer: block = 256 threads = 8 elements x 32 lanes, 4 cols/lane.
// nm bf16 in, fp32 add, em bf16 out.  (log2 domain: product = add)
// ---------------------------------------------------------------------------
__global__ void __launch_bounds__(256) k_prod_layer(const unsigned short* __restrict__ nm,
                                                    const int* __restrict__ pids,
                                                    unsigned short* __restrict__ em) {
    int g = blockIdx.x;
    int chunk = g & 7;
    int sub = threadIdx.x >> 5;
    int lane = threadIdx.x & 31;
    int e = (g >> 3) * 8 + sub;
    int p0 = pids[e * 2 + 0];
    int p1 = pids[e * 2 + 1];
    int b = chunk * W + lane * 4;
    ushort4 a = *(const ushort4*)(nm + (size_t)p0 * BB + b);
    ushort4 c = *(const ushort4*)(nm + (size_t)p1 * BB + b);
    ushort4 o;
    o.x = f2bf(bf2f(a.x) + bf2f(c.x));
    o.y = f2bf(bf2f(a.y) + bf2f(c.y));
    o.z = f2bf(bf2f(a.z) + bf2f(c.z));
    o.w = f2bf(bf2f(a.w) + bf2f(c.w));
    *(ushort4*)(em + (size_t)e * BB + b) = o;
}

// ---------------------------------------------------------------------------
// sum layer (log2 domain): block = 256 threads = 8 sum nodes x 32 lanes,
// 4 cols/lane. em bf16 in, children in 2 groups of 16 + online combine,
// nm bf16 out.
// ---------------------------------------------------------------------------
__global__ void __launch_bounds__(256) k_sum_layer(const unsigned short* __restrict__ em,
                                                   const int* __restrict__ cids,
                                                   const float* __restrict__ w,
                                                   unsigned short* __restrict__ out,
                                                   int S) {
    int g = blockIdx.x;
    int chunk = g & 7;
    int sub = threadIdx.x >> 5;
    int lane = threadIdx.x & 31;
    int s = (g >> 3) * 8 + sub;
    __shared__ float slw[8][CC];
    __shared__ int scid[8][CC];
    if (s < S) {
        float lw = w[s * CC + lane];
        float m = lw;
        #pragma unroll
        for (int d = 16; d; d >>= 1) m = fmaxf(m, __shfl_xor(m, d, 32));
        float su0 = __expf(lw - m);
        #pragma unroll
        for (int d = 16; d; d >>= 1) su0 += __shfl_xor(su0, d, 32);
        slw[sub][lane] = (lw - m) * LOG2E - flog2(su0);
        scid[sub][lane] = cids[s * CC + lane] - 1;
    }
    __syncthreads();
    if (s >= S) return;
    int b = chunk * W + lane * 4;

    float4 mx, su;
    #pragma unroll
    for (int grp2 = 0; grp2 < 2; ++grp2) {
        float4 v[16];
        float4 gmx = {-INFINITY, -INFINITY, -INFINITY, -INFINITY};
        #pragma unroll
        for (int c = 0; c < 16; ++c) {
            int cc = grp2 * 16 + c;
            ushort4 t4 = *(const ushort4*)(em + (size_t)scid[sub][cc] * BB + b);
            float lw = slw[sub][cc];
            float4 t;
            t.x = bf2f(t4.x) + lw; t.y = bf2f(t4.y) + lw;
            t.z = bf2f(t4.z) + lw; t.w = bf2f(t4.w) + lw;
            v[c] = t;
            gmx.x = fmaxf(gmx.x, t.x); gmx.y = fmaxf(gmx.y, t.y);
            gmx.z = fmaxf(gmx.z, t.z); gmx.w = fmaxf(gmx.w, t.w);
        }
        float4 gsu = {0.f, 0.f, 0.f, 0.f};
        #pragma unroll
        for (int c = 0; c < 16; ++c) {
            gsu.x += fexp2(v[c].x - gmx.x);
            gsu.y += fexp2(v[c].y - gmx.y);
            gsu.z += fexp2(v[c].z - gmx.z);
            gsu.w += fexp2(v[c].w - gmx.w);
        }
        if (grp2 == 0) {
            mx = gmx; su = gsu;
        } else {
            float4 nmx;
            nmx.x = fmaxf(mx.x, gmx.x); nmx.y = fmaxf(mx.y, gmx.y);
            nmx.z = fmaxf(mx.z, gmx.z); nmx.w = fmaxf(mx.w, gmx.w);
            su.x = su.x * fexp2(mx.x - nmx.x) + gsu.x * fexp2(gmx.x - nmx.x);
            su.y = su.y * fexp2(mx.y - nmx.y) + gsu.y * fexp2(gmx.y - nmx.y);
            su.z = su.z * fexp2(mx.z - nmx.z) + gsu.z * fexp2(gmx.z - nmx.z);
            su.w = su.w * fexp2(mx.w - nmx.w) + gsu.w * fexp2(gmx.w - nmx.w);
            mx = nmx;
        }
    }
    ushort4 o;
    o.x = f2bf(mx.x + flog2(su.x));
    o.y = f2bf(mx.y + flog2(su.y));
    o.z = f2bf(mx.z + flog2(su.z));
    o.w = f2bf(mx.w + flog2(su.w));
    *(ushort4*)(out + (size_t)s * BB + b) = o;
}

// ---------------------------------------------------------------------------
// fused root (prod4+sum4): root references only 32 of the 1024 layer-4
// elements; compute them on the fly from nm (bf16). 8 blocks x 128 threads.
// Output fp32, ln domain.
// ---------------------------------------------------------------------------
__global__ void __launch_bounds__(W) k_root(const unsigned short* __restrict__ nm,
                                            const int* __restrict__ pids,
                                            const int* __restrict__ cids,
                                            const float* __restrict__ w,
                                            float* __restrict__ out) {
    int chunk = blockIdx.x;
    int t = threadIdx.x;
    __shared__ float slw[CC];
    __shared__ int sp0[CC], sp1[CC];
    if (t < CC) {
        float lw = w[t];
        float m = lw;
        #pragma unroll
        for (int d = 16; d; d >>= 1) m = fmaxf(m, __shfl_xor(m, d, 32));
        float su = __expf(lw - m);
        #pragma unroll
        for (int d = 16; d; d >>= 1) su += __shfl_xor(su, d, 32);
        slw[t] = (lw - m) * LOG2E - flog2(su);
        int e = cids[t] - 1;
        sp0[t] = pids[e * 2 + 0];
        sp1[t] = pids[e * 2 + 1];
    }
    __syncthreads();
    int b = chunk * W + t;
    float v[CC];
    float mx = -INFINITY;
    #pragma unroll
    for (int c = 0; c < CC; ++c) {
        v[c] = bf2f(nm[(size_t)sp0[c] * BB + b]) + bf2f(nm[(size_t)sp1[c] * BB + b]) + slw[c];
        mx = fmaxf(mx, v[c]);
    }
    float su = 0.f;
    #pragma unroll
    for (int c = 0; c < CC; ++c) su += fexp2(v[c] - mx);
    out[b] = (mx + flog2(su)) * LN2;
}

// ---------------------------------------------------------------------------
// Launch: 9 dispatches. All intermediates bf16 in log2 domain; dispatch
// boundaries give free inter-phase L2 persistence (measured R2/R6/R9).
// ---------------------------------------------------------------------------
extern "C" void kernel_launch(void* const* d_in, const int* in_sizes, int n_in,
                              void* d_out, int out_size, void* d_ws, size_t ws_size,
                              hipStream_t stream) {
    const int*   x         = (const int*)  d_in[0];
    const float* in_logits = (const float*)d_in[1];
    const float* w1        = (const float*)d_in[2];
    const float* w2        = (const float*)d_in[3];
    const float* w3        = (const float*)d_in[4];
    const float* w4        = (const float*)d_in[5];
    const int*   pids1     = (const int*)  d_in[6];
    const int*   pids2     = (const int*)  d_in[7];
    const int*   pids3     = (const int*)  d_in[8];
    const int*   pids4     = (const int*)  d_in[9];
    const int*   cids1     = (const int*)  d_in[10];
    const int*   cids2     = (const int*)  d_in[11];
    const int*   cids3     = (const int*)  d_in[12];
    const int*   cids4     = (const int*)  d_in[13];
    float* out = (float*)d_out;

    unsigned short* nm = (unsigned short*)d_ws;             // 15361*1024 bf16
    unsigned short* em = nm + (size_t)15361 * BB;           //  8192*1024 bf16
    unsigned short* lp = em + (size_t)8192 * BB;            //  8192*64 bf16
    int*            xt = (int*)(lp + (size_t)N0 * KK);      //   256*1024 i32

    k_prep        <<<1024 + N0 / 4, 256, 0, stream>>>(x, in_logits, xt, lp);
    k_input_gather<<<(N0 / 8) * 8, W, 0, stream>>>(lp, xt, nm);

    // layer pair 1: E=8192 -> S=4096 (global ids 8193..12288)
    k_prod_layer<<<(8192 / 8) * 8, 256, 0, stream>>>(nm, pids1, em);
    k_sum_layer <<<(4096 / 8) * 8, 256, 0, stream>>>(em, cids1, w1, nm + (size_t)8193 * BB, 4096);
    // layer pair 2: E=4096 -> S=2048 (ids 12289..14336)
    k_prod_layer<<<(4096 / 8) * 8, 256, 0, stream>>>(nm, pids2, em);
    k_sum_layer <<<(2048 / 8) * 8, 256, 0, stream>>>(em, cids2, w2, nm + (size_t)12289 * BB, 2048);
    // layer pair 3: E=2048 -> S=1024 (ids 14337..15360)
    k_prod_layer<<<(2048 / 8) * 8, 256, 0, stream>>>(nm, pids3, em);
    k_sum_layer <<<(1024 / 8) * 8, 256, 0, stream>>>(em, cids3, w3, nm + (size_t)14337 * BB, 1024);
    // layer pair 4 fused: root references only 32 elements -> on the fly
    k_root<<<8, W, 0, stream>>>(nm, pids4, cids4, w4, out);
}

// Round 11
// 158.835 us; speedup vs baseline: 7.5183x; 1.0571x over previous
//
#include <hip/hip_runtime.h>
#include <math.h>

#define BB 1024   // batch
#define VV 256    // variables
#define KK 64     // categories
#define N0 8192   // input nodes
#define CC 32     // sum-node children

#define LOG2E 1.4426950408889634f
#define LN2   0.6931471805599453f

static __device__ __forceinline__ float fexp2(float x) { return __builtin_amdgcn_exp2f(x); }
static __device__ __forceinline__ float flog2(float x) { return __builtin_amdgcn_logf(x); }
static __device__ __forceinline__ float bf2f(unsigned short u) {
    union { unsigned int i; float f; } c; c.i = (unsigned int)u << 16; return c.f;
}
static __device__ __forceinline__ unsigned short f2bf(float f) {
    union { float f; unsigned int i; } c; c.f = f;
    unsigned int r = c.i + 0x7FFFu + ((c.i >> 16) & 1u);  // RNE
    return (unsigned short)(r >> 16);
}
// 32-lane log2-softmax (lane holds one weight)
static __device__ __forceinline__ float lsm32(float lw) {
    float m = lw;
    #pragma unroll
    for (int d = 16; d; d >>= 1) m = fmaxf(m, __shfl_xor(m, d, 32));
    float s = __expf(lw - m);
    #pragma unroll
    for (int d = 16; d; d >>= 1) s += __shfl_xor(s, d, 32);
    return (lw - m) * LOG2E - flog2(s);
}

// ---------------------------------------------------------------------------
// prep: one dispatch packing everything the mega kernel streams:
//  bid <  2048 : lpT[k][i] = log2_softmax(in_logits[i])[k]  (bf16, TRANSPOSED)
//  bid <  2944 : spk[n][c] = (cid_local) | (bf16 log2-weight << 16)   n=sum node
//  bid <  3000 : ppk[e]    = (p0_local) | (p1_local << 16)            e=element
//  bid == 3000 : rpk[c]    = {p0_local, p1_local, bf16 lw, 0}         root
// ---------------------------------------------------------------------------
__global__ void __launch_bounds__(256) k_prep(
        const float* __restrict__ logits,
        const float* __restrict__ w1, const float* __restrict__ w2,
        const float* __restrict__ w3, const float* __restrict__ w4,
        const int* __restrict__ cids1, const int* __restrict__ cids2,
        const int* __restrict__ cids3, const int* __restrict__ cids4,
        const int* __restrict__ pids1, const int* __restrict__ pids2,
        const int* __restrict__ pids3, const int* __restrict__ pids4,
        unsigned short* __restrict__ lpT, unsigned int* __restrict__ ppk,
        unsigned int* __restrict__ spk, ushort4* __restrict__ rpk) {
    int bid = blockIdx.x, tid = threadIdx.x;
    __shared__ unsigned short tile[4][64];
    if (bid < 2048) {
        int i = bid * 4 + (tid >> 6);
        int k = tid & 63;
        float l = logits[(size_t)i * KK + k];
        float m = l;
        #pragma unroll
        for (int d = 32; d; d >>= 1) m = fmaxf(m, __shfl_xor(m, d));
        float s = __expf(l - m);
        #pragma unroll
        for (int d = 32; d; d >>= 1) s += __shfl_xor(s, d);
        tile[tid >> 6][k] = f2bf((l - m) * LOG2E - flog2(s));
        __syncthreads();
        if (tid < 64) {  // transposed store: 4 consecutive i per k
            ushort4 o;
            o.x = tile[0][tid]; o.y = tile[1][tid];
            o.z = tile[2][tid]; o.w = tile[3][tid];
            *(ushort4*)(lpT + (size_t)tid * N0 + bid * 4) = o;
        }
    } else if (bid < 2944) {
        int n = (bid - 2048) * 8 + (tid >> 5);
        int lane = tid & 31;
        if (n < 7168) {
            const float* wsrc; const int* csrc;
            if (n < 4096)      { wsrc = w1 + (size_t)n * CC;          csrc = cids1 + (size_t)n * CC; }
            else if (n < 6144) { wsrc = w2 + (size_t)(n - 4096) * CC; csrc = cids2 + (size_t)(n - 4096) * CC; }
            else               { wsrc = w3 + (size_t)(n - 6144) * CC; csrc = cids3 + (size_t)(n - 6144) * CC; }
            float lwn = lsm32(wsrc[lane]);
            unsigned int cid = (unsigned int)(csrc[lane] - 1);
            spk[(size_t)n * CC + lane] = cid | ((unsigned int)f2bf(lwn) << 16);
        }
    } else if (bid < 3000) {
        int idx = (bid - 2944) * 256 + tid;  // 14336 elements total
        int p0, p1;
        if (idx < 8192)       { p0 = pids1[idx * 2] - 1;                p1 = pids1[idx * 2 + 1] - 1; }
        else if (idx < 12288) { int e = idx - 8192;  p0 = pids2[e * 2] - 8193;  p1 = pids2[e * 2 + 1] - 8193; }
        else                  { int e = idx - 12288; p0 = pids3[e * 2] - 12289; p1 = pids3[e * 2 + 1] - 12289; }
        ppk[idx] = (unsigned int)p0 | ((unsigned int)p1 << 16);
    } else {
        if (tid < CC) {
            float lwn = lsm32(w4[tid]);
            int e = cids4[tid] - 1;
            ushort4 r;
            r.x = (unsigned short)(pids4[e * 2]     - 14337);
            r.y = (unsigned short)(pids4[e * 2 + 1] - 14337);
            r.z = f2bf(lwn); r.w = 0;
            rpk[tid] = r;
        }
    }
}

// ---------------------------------------------------------------------------
// One layer for a 4-column slice. prod: em[e] = nm[p0]+nm[p1] (bf16, log2
// domain). sum: per-thread whole-node 32-child logsumexp (2 groups of 16,
// online combine), writes nm[s]. Only __syncthreads between phases.
// ---------------------------------------------------------------------------
template <typename NMP>
static __device__ __forceinline__ void do_layer(
        NMP nm4, ushort4* em4,
        const unsigned int* __restrict__ pp, const unsigned int* __restrict__ sp,
        int E, int S, int tid) {
    for (int e = tid; e < E; e += 512) {
        unsigned int p = pp[e];
        ushort4 a = nm4[p & 0xFFFFu];
        ushort4 b = nm4[p >> 16];
        ushort4 o;
        o.x = f2bf(bf2f(a.x) + bf2f(b.x));
        o.y = f2bf(bf2f(a.y) + bf2f(b.y));
        o.z = f2bf(bf2f(a.z) + bf2f(b.z));
        o.w = f2bf(bf2f(a.w) + bf2f(b.w));
        em4[e] = o;
    }
    __syncthreads();
    for (int s = tid; s < S; s += 512) {
        const uint4* base = (const uint4*)(sp + (size_t)s * CC);
        float4 mx, su;
        #pragma unroll
        for (int g = 0; g < 2; ++g) {
            uint4 q0 = base[g * 4 + 0], q1 = base[g * 4 + 1];
            uint4 q2 = base[g * 4 + 2], q3 = base[g * 4 + 3];
            unsigned int uu[16] = {q0.x, q0.y, q0.z, q0.w, q1.x, q1.y, q1.z, q1.w,
                                   q2.x, q2.y, q2.z, q2.w, q3.x, q3.y, q3.z, q3.w};
            float4 v[16];
            float4 gmx = {-INFINITY, -INFINITY, -INFINITY, -INFINITY};
            #pragma unroll
            for (int c = 0; c < 16; ++c) {
                ushort4 t4 = em4[uu[c] & 0xFFFFu];
                float lw = bf2f((unsigned short)(uu[c] >> 16));
                float4 t;
                t.x = bf2f(t4.x) + lw; t.y = bf2f(t4.y) + lw;
                t.z = bf2f(t4.z) + lw; t.w = bf2f(t4.w) + lw;
                v[c] = t;
                gmx.x = fmaxf(gmx.x, t.x); gmx.y = fmaxf(gmx.y, t.y);
                gmx.z = fmaxf(gmx.z, t.z); gmx.w = fmaxf(gmx.w, t.w);
            }
            float4 gsu = {0.f, 0.f, 0.f, 0.f};
            #pragma unroll
            for (int c = 0; c < 16; ++c) {
                gsu.x += fexp2(v[c].x - gmx.x);
                gsu.y += fexp2(v[c].y - gmx.y);
                gsu.z += fexp2(v[c].z - gmx.z);
                gsu.w += fexp2(v[c].w - gmx.w);
            }
            if (g == 0) { mx = gmx; su = gsu; }
            else {
                float4 nmx;
                nmx.x = fmaxf(mx.x, gmx.x); nmx.y = fmaxf(mx.y, gmx.y);
                nmx.z = fmaxf(mx.z, gmx.z); nmx.w = fmaxf(mx.w, gmx.w);
                su.x = su.x * fexp2(mx.x - nmx.x) + gsu.x * fexp2(gmx.x - nmx.x);
                su.y = su.y * fexp2(mx.y - nmx.y) + gsu.y * fexp2(gmx.y - nmx.y);
                su.z = su.z * fexp2(mx.z - nmx.z) + gsu.z * fexp2(gmx.z - nmx.z);
                su.w = su.w * fexp2(mx.w - nmx.w) + gsu.w * fexp2(gmx.w - nmx.w);
                mx = nmx;
            }
        }
        ushort4 o;
        o.x = f2bf(mx.x + flog2(su.x));
        o.y = f2bf(mx.y + flog2(su.y));
        o.z = f2bf(mx.z + flog2(su.z));
        o.w = f2bf(mx.w + flog2(su.w));
        nm4[s] = o;
    }
    __syncthreads();
}

template <typename NMP>
static __device__ __forceinline__ void do_root(NMP nm4, const ushort4* __restrict__ rpk,
                                               float* __restrict__ out, int b0, int tid) {
    if (tid < 4) {
        int col = tid;
        float v[CC];
        float mx = -INFINITY;
        #pragma unroll
        for (int c = 0; c < CC; ++c) {
            ushort4 r = rpk[c];
            ushort4 a = nm4[r.x];
            ushort4 b = nm4[r.y];
            const unsigned short* ap = &a.x;
            const unsigned short* bp = &b.x;
            float t = bf2f(ap[col]) + bf2f(bp[col]) + bf2f(r.z);
            v[c] = t; mx = fmaxf(mx, t);
        }
        float s = 0.f;
        #pragma unroll
        for (int c = 0; c < CC; ++c) s += fexp2(v[c] - mx);
        out[b0 + col] = (mx + flog2(s)) * LN2;
    }
}

// ---------------------------------------------------------------------------
// mega A: block owns 4 batch cols; nm AND em slices both in LDS (135 KB,
// needs dynamic-LDS opt-in). Whole net, __syncthreads-only between phases.
// ---------------------------------------------------------------------------
__global__ void __launch_bounds__(512, 2) k_mega_lds(
        const int* __restrict__ x, const unsigned short* __restrict__ lpT,
        const unsigned int* __restrict__ ppk, const unsigned int* __restrict__ spk,
        const ushort4* __restrict__ rpk, float* __restrict__ out) {
    extern __shared__ ushort4 smem4[];
    ushort4* nm4 = smem4;                 // [8192] = 64 KB
    ushort4* em4 = smem4 + 8192;          // [8192] = 64 KB
    int* xv = (int*)(smem4 + 16384);      // [4][256] = 4 KB
    int tid = threadIdx.x;
    int b0 = blockIdx.x * 4;

    for (int t = tid; t < 1024; t += 512) {
        int c = t >> 8, v = t & 255;
        xv[t] = x[(b0 + c) * VV + v];
    }
    __syncthreads();
    for (int i = tid; i < N0; i += 512) {    // input gather via transposed lpT
        int v = i >> 5;
        ushort4 o;
        o.x = lpT[(size_t)xv[v]       * N0 + i];
        o.y = lpT[(size_t)xv[256 + v] * N0 + i];
        o.z = lpT[(size_t)xv[512 + v] * N0 + i];
        o.w = lpT[(size_t)xv[768 + v] * N0 + i];
        nm4[i] = o;
    }
    __syncthreads();
    do_layer(nm4, em4, ppk,         spk,          8192, 4096, tid);
    do_layer(nm4, em4, ppk + 8192,  spk + 131072, 4096, 2048, tid);
    do_layer(nm4, em4, ppk + 12288, spk + 196608, 2048, 1024, tid);
    do_root(nm4, rpk, out, b0, tid);
}

// ---------------------------------------------------------------------------
// mega B (fallback if >64KB LDS opt-in fails): em in LDS (64 KB exactly),
// nm in a per-block global slice.
// ---------------------------------------------------------------------------
__global__ void __launch_bounds__(512, 2) k_mega_glb(
        const int* __restrict__ x, const unsigned short* __restrict__ lpT,
        const unsigned int* __restrict__ ppk, const unsigned int* __restrict__ spk,
        const ushort4* __restrict__ rpk, ushort4* __restrict__ nmg,
        float* __restrict__ out) {
    extern __shared__ ushort4 smem4[];
    ushort4* em4 = smem4;                              // [8192] = 64 KB
    ushort4* nm4 = nmg + (size_t)blockIdx.x * 8192;    // global slice
    int tid = threadIdx.x;
    int b0 = blockIdx.x * 4;

    for (int i = tid; i < N0; i += 512) {
        int v = i >> 5;
        int x0 = x[(b0 + 0) * VV + v], x1 = x[(b0 + 1) * VV + v];
        int x2 = x[(b0 + 2) * VV + v], x3 = x[(b0 + 3) * VV + v];
        ushort4 o;
        o.x = lpT[(size_t)x0 * N0 + i];
        o.y = lpT[(size_t)x1 * N0 + i];
        o.z = lpT[(size_t)x2 * N0 + i];
        o.w = lpT[(size_t)x3 * N0 + i];
        nm4[i] = o;
    }
    __syncthreads();
    do_layer(nm4, em4, ppk,         spk,          8192, 4096, tid);
    do_layer(nm4, em4, ppk + 8192,  spk + 131072, 4096, 2048, tid);
    do_layer(nm4, em4, ppk + 12288, spk + 196608, 2048, 1024, tid);
    do_root(nm4, rpk, out, b0, tid);
}

// ---------------------------------------------------------------------------
// Launch: 2 dispatches (prep + mega). Deterministic A/B pick by whether the
// 135 KB dynamic-LDS opt-in succeeds (same decision every call).
// ---------------------------------------------------------------------------
extern "C" void kernel_launch(void* const* d_in, const int* in_sizes, int n_in,
                              void* d_out, int out_size, void* d_ws, size_t ws_size,
                              hipStream_t stream) {
    const int*   x         = (const int*)  d_in[0];
    const float* in_logits = (const float*)d_in[1];
    const float* w1        = (const float*)d_in[2];
    const float* w2        = (const float*)d_in[3];
    const float* w3        = (const float*)d_in[4];
    const float* w4        = (const float*)d_in[5];
    const int*   pids1     = (const int*)  d_in[6];
    const int*   pids2     = (const int*)  d_in[7];
    const int*   pids3     = (const int*)  d_in[8];
    const int*   pids4     = (const int*)  d_in[9];
    const int*   cids1     = (const int*)  d_in[10];
    const int*   cids2     = (const int*)  d_in[11];
    const int*   cids3     = (const int*)  d_in[12];
    const int*   cids4     = (const int*)  d_in[13];
    float* out = (float*)d_out;

    char* ws = (char*)d_ws;
    unsigned short* lpT = (unsigned short*)ws;                    // 64*8192 bf16 = 1 MB
    unsigned int*   ppk = (unsigned int*)(ws + 1048576);          // 14336 u32
    unsigned int*   spk = (unsigned int*)(ws + 1105920);          // 229376 u32
    ushort4*        rpk = (ushort4*)(ws + 2023424);               // 32 x 8 B
    ushort4*        nmg = (ushort4*)(ws + 2023936);               // 256*8192*8 B = 16 MB (B only)

    k_prep<<<3001, 256, 0, stream>>>(in_logits, w1, w2, w3, w4,
                                     cids1, cids2, cids3, cids4,
                                     pids1, pids2, pids3, pids4,
                                     lpT, ppk, spk, rpk);

    const int SMEM_A = 135168;  // 64K nm + 64K em + 4K xv
    const int SMEM_B = 65536;   // 64K em
    hipError_t e = hipFuncSetAttribute((const void*)k_mega_lds,
                                       hipFuncAttributeMaxDynamicSharedMemorySize, SMEM_A);
    if (e == hipSuccess) {
        k_mega_lds<<<256, 512, SMEM_A, stream>>>(x, lpT, ppk, spk, rpk, out);
    } else {
        (void)hipGetLastError();  // clear sticky error from failed opt-in
        k_mega_glb<<<256, 512, SMEM_B, stream>>>(x, lpT, ppk, spk, rpk, nmg, out);
    }
}

// Round 12
// 134.139 us; speedup vs baseline: 8.9025x; 1.1841x over previous
//
#include <hip/hip_runtime.h>
#include <math.h>

#define BB 1024   // batch
#define VV 256    // variables
#define KK 64     // categories
#define N0 8192   // input nodes
#define CC 32     // sum-node children

#define LOG2E 1.4426950408889634f
#define LN2   0.6931471805599453f
// layer-1 weight scale 2^13 centers linear-domain values near 2^0;
// accumulated scale at the root su is 2^(8*13) = 2^104.
#define W1SCALE 8192.0f
#define ROOT_LOG2_SCALE 104.0f

static __device__ __forceinline__ float flog2(float x) { return __builtin_amdgcn_logf(x); }
static __device__ __forceinline__ float bf2f(unsigned short u) {
    union { unsigned int i; float f; } c; c.i = (unsigned int)u << 16; return c.f;
}
static __device__ __forceinline__ unsigned short f2bf(float f) {
    union { float f; unsigned int i; } c; c.f = f;
    unsigned int r = c.i + 0x7FFFu + ((c.i >> 16) & 1u);  // RNE
    return (unsigned short)(r >> 16);
}

// ---------------------------------------------------------------------------
// prep: one dispatch packing everything the mega kernel streams (LINEAR dom):
//  bid <  2048 : lpT[k][i] = softmax(in_logits[i])[k]      (bf16, TRANSPOSED)
//  bid <  2944 : spk[n][c] = cid | (bf16 linear-weight <<16); layer1 w *= 2^13
//  bid <  3000 : ppk[e]    = p0_local | (p1_local << 16)
//  bid == 3000 : rpk[c]    = {p0_local, p1_local, bf16 softmax(w4), 0}
// ---------------------------------------------------------------------------
__global__ void __launch_bounds__(256) k_prep(
        const float* __restrict__ logits,
        const float* __restrict__ w1, const float* __restrict__ w2,
        const float* __restrict__ w3, const float* __restrict__ w4,
        const int* __restrict__ cids1, const int* __restrict__ cids2,
        const int* __restrict__ cids3, const int* __restrict__ cids4,
        const int* __restrict__ pids1, const int* __restrict__ pids2,
        const int* __restrict__ pids3, const int* __restrict__ pids4,
        unsigned short* __restrict__ lpT, unsigned int* __restrict__ ppk,
        unsigned int* __restrict__ spk, ushort4* __restrict__ rpk) {
    int bid = blockIdx.x, tid = threadIdx.x;
    __shared__ unsigned short tile[4][64];
    if (bid < 2048) {
        int i = bid * 4 + (tid >> 6);
        int k = tid & 63;
        float l = logits[(size_t)i * KK + k];
        float m = l;
        #pragma unroll
        for (int d = 32; d; d >>= 1) m = fmaxf(m, __shfl_xor(m, d));
        float e = __expf(l - m);
        float s = e;
        #pragma unroll
        for (int d = 32; d; d >>= 1) s += __shfl_xor(s, d);
        tile[tid >> 6][k] = f2bf(e / s);          // linear softmax prob
        __syncthreads();
        if (tid < 64) {  // transposed store: 4 consecutive i per k
            ushort4 o;
            o.x = tile[0][tid]; o.y = tile[1][tid];
            o.z = tile[2][tid]; o.w = tile[3][tid];
            *(ushort4*)(lpT + (size_t)tid * N0 + bid * 4) = o;
        }
    } else if (bid < 2944) {
        int n = (bid - 2048) * 8 + (tid >> 5);
        int lane = tid & 31;
        if (n < 7168) {
            const float* wsrc; const int* csrc; float scale;
            if (n < 4096)      { wsrc = w1 + (size_t)n * CC;          csrc = cids1 + (size_t)n * CC;          scale = W1SCALE; }
            else if (n < 6144) { wsrc = w2 + (size_t)(n - 4096) * CC; csrc = cids2 + (size_t)(n - 4096) * CC; scale = 1.0f; }
            else               { wsrc = w3 + (size_t)(n - 6144) * CC; csrc = cids3 + (size_t)(n - 6144) * CC; scale = 1.0f; }
            float lw = wsrc[lane];
            float m = lw;
            #pragma unroll
            for (int d = 16; d; d >>= 1) m = fmaxf(m, __shfl_xor(m, d, 32));
            float e = __expf(lw - m);
            float s = e;
            #pragma unroll
            for (int d = 16; d; d >>= 1) s += __shfl_xor(s, d, 32);
            unsigned int cid = (unsigned int)(csrc[lane] - 1);
            spk[(size_t)n * CC + lane] = cid | ((unsigned int)f2bf(e / s * scale) << 16);
        }
    } else if (bid < 3000) {
        int idx = (bid - 2944) * 256 + tid;  // 14336 elements total
        int p0, p1;
        if (idx < 8192)       { p0 = pids1[idx * 2] - 1;                p1 = pids1[idx * 2 + 1] - 1; }
        else if (idx < 12288) { int e = idx - 8192;  p0 = pids2[e * 2] - 8193;  p1 = pids2[e * 2 + 1] - 8193; }
        else                  { int e = idx - 12288; p0 = pids3[e * 2] - 12289; p1 = pids3[e * 2 + 1] - 12289; }
        ppk[idx] = (unsigned int)p0 | ((unsigned int)p1 << 16);
    } else {
        if (tid < CC) {
            float lw = w4[tid];
            float m = lw;
            #pragma unroll
            for (int d = 16; d; d >>= 1) m = fmaxf(m, __shfl_xor(m, d, 32));
            float e = __expf(lw - m);
            float s = e;
            #pragma unroll
            for (int d = 16; d; d >>= 1) s += __shfl_xor(s, d, 32);
            int el = cids4[tid] - 1;
            ushort4 r;
            r.x = (unsigned short)(pids4[el * 2]     - 14337);
            r.y = (unsigned short)(pids4[el * 2 + 1] - 14337);
            r.z = f2bf(e / s); r.w = 0;
            rpk[tid] = r;
        }
    }
}

// ---------------------------------------------------------------------------
// One layer for a 4-column slice, linear domain.
// prod: em[e] = nm[p0]*nm[p1] (bf16). sum: su = sum_c w_c * em[cid_c] (pure
// FMA, all terms positive, fp32 accumulate), write bf16. No exp/log/max.
// ---------------------------------------------------------------------------
template <typename NMP>
static __device__ __forceinline__ void do_layer(
        NMP nm4, ushort4* em4,
        const unsigned int* __restrict__ pp, const unsigned int* __restrict__ sp,
        int E, int S, int tid, int nthr) {
    for (int e = tid; e < E; e += nthr) {
        unsigned int p = pp[e];
        ushort4 a = nm4[p & 0xFFFFu];
        ushort4 b = nm4[p >> 16];
        ushort4 o;
        o.x = f2bf(bf2f(a.x) * bf2f(b.x));
        o.y = f2bf(bf2f(a.y) * bf2f(b.y));
        o.z = f2bf(bf2f(a.z) * bf2f(b.z));
        o.w = f2bf(bf2f(a.w) * bf2f(b.w));
        em4[e] = o;
    }
    __syncthreads();
    for (int s = tid; s < S; s += nthr) {
        const uint4* base = (const uint4*)(sp + (size_t)s * CC);
        float4 su = {0.f, 0.f, 0.f, 0.f};
        #pragma unroll
        for (int q = 0; q < 8; ++q) {
            uint4 qq = base[q];
            unsigned int uu[4] = {qq.x, qq.y, qq.z, qq.w};
            #pragma unroll
            for (int c = 0; c < 4; ++c) {
                ushort4 t4 = em4[uu[c] & 0xFFFFu];
                float w = bf2f((unsigned short)(uu[c] >> 16));
                su.x = fmaf(bf2f(t4.x), w, su.x);
                su.y = fmaf(bf2f(t4.y), w, su.y);
                su.z = fmaf(bf2f(t4.z), w, su.z);
                su.w = fmaf(bf2f(t4.w), w, su.w);
            }
        }
        ushort4 o;
        o.x = f2bf(su.x); o.y = f2bf(su.y);
        o.z = f2bf(su.z); o.w = f2bf(su.w);
        nm4[s] = o;
    }
    __syncthreads();
}

template <typename NMP>
static __device__ __forceinline__ void do_root(NMP nm4, const ushort4* __restrict__ rpk,
                                               float* __restrict__ out, int b0, int tid) {
    if (tid < 4) {
        int col = tid;
        float su = 0.f;
        #pragma unroll
        for (int c = 0; c < CC; ++c) {
            ushort4 r = rpk[c];
            ushort4 a = nm4[r.x];
            ushort4 b = nm4[r.y];
            const unsigned short* ap = &a.x;
            const unsigned short* bp = &b.x;
            su = fmaf(bf2f(ap[col]) * bf2f(bp[col]), bf2f(r.z), su);
        }
        out[b0 + col] = (flog2(su) - ROOT_LOG2_SCALE) * LN2;
    }
}

// ---------------------------------------------------------------------------
// mega A: block owns 4 batch cols; nm AND em slices in LDS (135 KB, dynamic
// opt-in). 1024 threads (16 waves/CU) for latency hiding. Whole net,
// __syncthreads-only between phases.
// ---------------------------------------------------------------------------
__global__ void __launch_bounds__(1024, 1) k_mega_lds(
        const int* __restrict__ x, const unsigned short* __restrict__ lpT,
        const unsigned int* __restrict__ ppk, const unsigned int* __restrict__ spk,
        const ushort4* __restrict__ rpk, float* __restrict__ out) {
    extern __shared__ ushort4 smem4[];
    ushort4* nm4 = smem4;                 // [8192] = 64 KB
    ushort4* em4 = smem4 + 8192;          // [8192] = 64 KB
    int* xv = (int*)(smem4 + 16384);      // [4][256] = 4 KB
    int tid = threadIdx.x;
    int b0 = blockIdx.x * 4;

    if (tid < 1024) {
        int c = tid >> 8, v = tid & 255;
        xv[tid] = x[(b0 + c) * VV + v];
    }
    __syncthreads();
    for (int i = tid; i < N0; i += 1024) {   // input gather via transposed lpT
        int v = i >> 5;
        ushort4 o;
        o.x = lpT[(size_t)xv[v]       * N0 + i];
        o.y = lpT[(size_t)xv[256 + v] * N0 + i];
        o.z = lpT[(size_t)xv[512 + v] * N0 + i];
        o.w = lpT[(size_t)xv[768 + v] * N0 + i];
        nm4[i] = o;
    }
    __syncthreads();
    do_layer(nm4, em4, ppk,         spk,          8192, 4096, tid, 1024);
    do_layer(nm4, em4, ppk + 8192,  spk + 131072, 4096, 2048, tid, 1024);
    do_layer(nm4, em4, ppk + 12288, spk + 196608, 2048, 1024, tid, 1024);
    do_root(nm4, rpk, out, b0, tid);
}

// ---------------------------------------------------------------------------
// mega B (fallback if >64KB LDS opt-in fails): em in LDS (64 KB), nm in a
// per-block global slice.
// ---------------------------------------------------------------------------
__global__ void __launch_bounds__(1024, 1) k_mega_glb(
        const int* __restrict__ x, const unsigned short* __restrict__ lpT,
        const unsigned int* __restrict__ ppk, const unsigned int* __restrict__ spk,
        const ushort4* __restrict__ rpk, ushort4* __restrict__ nmg,
        float* __restrict__ out) {
    extern __shared__ ushort4 smem4[];
    ushort4* em4 = smem4;                              // [8192] = 64 KB
    ushort4* nm4 = nmg + (size_t)blockIdx.x * 8192;    // global slice
    int tid = threadIdx.x;
    int b0 = blockIdx.x * 4;

    for (int i = tid; i < N0; i += 1024) {
        int v = i >> 5;
        int x0 = x[(b0 + 0) * VV + v], x1 = x[(b0 + 1) * VV + v];
        int x2 = x[(b0 + 2) * VV + v], x3 = x[(b0 + 3) * VV + v];
        ushort4 o;
        o.x = lpT[(size_t)x0 * N0 + i];
        o.y = lpT[(size_t)x1 * N0 + i];
        o.z = lpT[(size_t)x2 * N0 + i];
        o.w = lpT[(size_t)x3 * N0 + i];
        nm4[i] = o;
    }
    __syncthreads();
    do_layer(nm4, em4, ppk,         spk,          8192, 4096, tid, 1024);
    do_layer(nm4, em4, ppk + 8192,  spk + 131072, 4096, 2048, tid, 1024);
    do_layer(nm4, em4, ppk + 12288, spk + 196608, 2048, 1024, tid, 1024);
    do_root(nm4, rpk, out, b0, tid);
}

// ---------------------------------------------------------------------------
// Launch: 2 dispatches (prep + mega). Deterministic A/B pick by whether the
// 135 KB dynamic-LDS opt-in succeeds.
// ---------------------------------------------------------------------------
extern "C" void kernel_launch(void* const* d_in, const int* in_sizes, int n_in,
                              void* d_out, int out_size, void* d_ws, size_t ws_size,
                              hipStream_t stream) {
    const int*   x         = (const int*)  d_in[0];
    const float* in_logits = (const float*)d_in[1];
    const float* w1        = (const float*)d_in[2];
    const float* w2        = (const float*)d_in[3];
    const float* w3        = (const float*)d_in[4];
    const float* w4        = (const float*)d_in[5];
    const int*   pids1     = (const int*)  d_in[6];
    const int*   pids2     = (const int*)  d_in[7];
    const int*   pids3     = (const int*)  d_in[8];
    const int*   pids4     = (const int*)  d_in[9];
    const int*   cids1     = (const int*)  d_in[10];
    const int*   cids2     = (const int*)  d_in[11];
    const int*   cids3     = (const int*)  d_in[12];
    const int*   cids4     = (const int*)  d_in[13];
    float* out = (float*)d_out;

    char* ws = (char*)d_ws;
    unsigned short* lpT = (unsigned short*)ws;                    // 64*8192 bf16 = 1 MB
    unsigned int*   ppk = (unsigned int*)(ws + 1048576);          // 14336 u32
    unsigned int*   spk = (unsigned int*)(ws + 1105920);          // 229376 u32
    ushort4*        rpk = (ushort4*)(ws + 2023424);               // 32 x 8 B
    ushort4*        nmg = (ushort4*)(ws + 2023936);               // 256*8192*8 B = 16 MB (B only)

    k_prep<<<3001, 256, 0, stream>>>(in_logits, w1, w2, w3, w4,
                                     cids1, cids2, cids3, cids4,
                                     pids1, pids2, pids3, pids4,
                                     lpT, ppk, spk, rpk);

    const int SMEM_A = 135168;  // 64K nm + 64K em + 4K xv
    const int SMEM_B = 65536;   // 64K em
    hipError_t e = hipFuncSetAttribute((const void*)k_mega_lds,
                                       hipFuncAttributeMaxDynamicSharedMemorySize, SMEM_A);
    if (e == hipSuccess) {
        k_mega_lds<<<256, 1024, SMEM_A, stream>>>(x, lpT, ppk, spk, rpk, out);
    } else {
        (void)hipGetLastError();  // clear sticky error from failed opt-in
        hipFuncSetAttribute((const void*)k_mega_glb,
                            hipFuncAttributeMaxDynamicSharedMemorySize, SMEM_B);
        k_mega_glb<<<256, 1024, SMEM_B, stream>>>(x, lpT, ppk, spk, rpk, nmg, out);
    }
}

// Round 13
// 125.919 us; speedup vs baseline: 9.4837x; 1.0653x over previous
//
#include <hip/hip_runtime.h>
#include <math.h>

#define BB 1024   // batch
#define VV 256    // variables
#define KK 64     // categories
#define N0 8192   // input nodes
#define CC 32     // sum-node children

#define LOG2E 1.4426950408889634f
#define LN2   0.6931471805599453f
// layer-1 weight scale 2^13 centers linear-domain values near 2^0;
// accumulated scale at the root su is 2^(8*13) = 2^104.
#define W1SCALE 8192.0f
#define ROOT_LOG2_SCALE 104.0f

static __device__ __forceinline__ float flog2(float x) { return __builtin_amdgcn_logf(x); }
static __device__ __forceinline__ float bf2f(unsigned short u) {
    union { unsigned int i; float f; } c; c.i = (unsigned int)u << 16; return c.f;
}
static __device__ __forceinline__ unsigned short f2bf(float f) {
    union { float f; unsigned int i; } c; c.f = f;
    unsigned int r = c.i + 0x7FFFu + ((c.i >> 16) & 1u);  // RNE
    return (unsigned short)(r >> 16);
}

// ---------------------------------------------------------------------------
// prep: one dispatch packing everything the mega kernel streams (linear dom):
//  bid <  2048 : lpT[k][i] = softmax(in_logits[i])[k]      (bf16, TRANSPOSED)
//  bid <  2944 : spk[n][c] = cid | (bf16 linear-weight <<16); layer1 w *= 2^13
//  bid <  3000 : ppk[e]    = p0_local | (p1_local << 16)
//  bid == 3000 : rpk[c]    = {p0_local, p1_local, bf16 softmax(w4), 0}
// ---------------------------------------------------------------------------
__global__ void __launch_bounds__(256) k_prep(
        const float* __restrict__ logits,
        const float* __restrict__ w1, const float* __restrict__ w2,
        const float* __restrict__ w3, const float* __restrict__ w4,
        const int* __restrict__ cids1, const int* __restrict__ cids2,
        const int* __restrict__ cids3, const int* __restrict__ cids4,
        const int* __restrict__ pids1, const int* __restrict__ pids2,
        const int* __restrict__ pids3, const int* __restrict__ pids4,
        unsigned short* __restrict__ lpT, unsigned int* __restrict__ ppk,
        unsigned int* __restrict__ spk, ushort4* __restrict__ rpk) {
    int bid = blockIdx.x, tid = threadIdx.x;
    __shared__ unsigned short tile[4][64];
    if (bid < 2048) {
        int i = bid * 4 + (tid >> 6);
        int k = tid & 63;
        float l = logits[(size_t)i * KK + k];
        float m = l;
        #pragma unroll
        for (int d = 32; d; d >>= 1) m = fmaxf(m, __shfl_xor(m, d));
        float e = __expf(l - m);
        float s = e;
        #pragma unroll
        for (int d = 32; d; d >>= 1) s += __shfl_xor(s, d);
        tile[tid >> 6][k] = f2bf(e / s);          // linear softmax prob
        __syncthreads();
        if (tid < 64) {  // transposed store: 4 consecutive i per k
            ushort4 o;
            o.x = tile[0][tid]; o.y = tile[1][tid];
            o.z = tile[2][tid]; o.w = tile[3][tid];
            *(ushort4*)(lpT + (size_t)tid * N0 + bid * 4) = o;
        }
    } else if (bid < 2944) {
        int n = (bid - 2048) * 8 + (tid >> 5);
        int lane = tid & 31;
        if (n < 7168) {
            const float* wsrc; const int* csrc; float scale;
            if (n < 4096)      { wsrc = w1 + (size_t)n * CC;          csrc = cids1 + (size_t)n * CC;          scale = W1SCALE; }
            else if (n < 6144) { wsrc = w2 + (size_t)(n - 4096) * CC; csrc = cids2 + (size_t)(n - 4096) * CC; scale = 1.0f; }
            else               { wsrc = w3 + (size_t)(n - 6144) * CC; csrc = cids3 + (size_t)(n - 6144) * CC; scale = 1.0f; }
            float lw = wsrc[lane];
            float m = lw;
            #pragma unroll
            for (int d = 16; d; d >>= 1) m = fmaxf(m, __shfl_xor(m, d, 32));
            float e = __expf(lw - m);
            float s = e;
            #pragma unroll
            for (int d = 16; d; d >>= 1) s += __shfl_xor(s, d, 32);
            unsigned int cid = (unsigned int)(csrc[lane] - 1);
            spk[(size_t)n * CC + lane] = cid | ((unsigned int)f2bf(e / s * scale) << 16);
        }
    } else if (bid < 3000) {
        int idx = (bid - 2944) * 256 + tid;  // 14336 elements total
        int p0, p1;
        if (idx < 8192)       { p0 = pids1[idx * 2] - 1;                p1 = pids1[idx * 2 + 1] - 1; }
        else if (idx < 12288) { int e = idx - 8192;  p0 = pids2[e * 2] - 8193;  p1 = pids2[e * 2 + 1] - 8193; }
        else                  { int e = idx - 12288; p0 = pids3[e * 2] - 12289; p1 = pids3[e * 2 + 1] - 12289; }
        ppk[idx] = (unsigned int)p0 | ((unsigned int)p1 << 16);
    } else {
        if (tid < CC) {
            float lw = w4[tid];
            float m = lw;
            #pragma unroll
            for (int d = 16; d; d >>= 1) m = fmaxf(m, __shfl_xor(m, d, 32));
            float e = __expf(lw - m);
            float s = e;
            #pragma unroll
            for (int d = 16; d; d >>= 1) s += __shfl_xor(s, d, 32);
            int el = cids4[tid] - 1;
            ushort4 r;
            r.x = (unsigned short)(pids4[el * 2]     - 14337);
            r.y = (unsigned short)(pids4[el * 2 + 1] - 14337);
            r.z = f2bf(e / s); r.w = 0;
            rpk[tid] = r;
        }
    }
}

// ---------------------------------------------------------------------------
// One layer for a 4-column slice, linear domain, load-batched.
// prod: em[e] = nm[p0]*nm[p1], 4 elements batched (8 ds loads in flight).
// sum: per node, 2 groups of 16 children: 16 ds_read_b64 issued back-to-back
// into a register array (single waitcnt), then 64 FMAs.
// ---------------------------------------------------------------------------
template <typename NMP>
static __device__ __forceinline__ void do_layer(
        NMP nm4, ushort4* em4,
        const unsigned int* __restrict__ pp, const unsigned int* __restrict__ sp,
        int E, int S, int tid, int nthr) {
    for (int e = tid; e < E; e += nthr * 4) {
        unsigned int pw[4];
        ushort4 av[4], bv[4];
        int cnt = 0;
        #pragma unroll
        for (int j = 0; j < 4; ++j) {
            int ee = e + j * nthr;
            if (ee < E) { pw[j] = pp[ee]; ++cnt; }
        }
        #pragma unroll
        for (int j = 0; j < 4; ++j) {
            if (j < cnt) { av[j] = nm4[pw[j] & 0xFFFFu]; bv[j] = nm4[pw[j] >> 16]; }
        }
        #pragma unroll
        for (int j = 0; j < 4; ++j) {
            if (j < cnt) {
                ushort4 o;
                o.x = f2bf(bf2f(av[j].x) * bf2f(bv[j].x));
                o.y = f2bf(bf2f(av[j].y) * bf2f(bv[j].y));
                o.z = f2bf(bf2f(av[j].z) * bf2f(bv[j].z));
                o.w = f2bf(bf2f(av[j].w) * bf2f(bv[j].w));
                em4[e + j * nthr] = o;
            }
        }
    }
    __syncthreads();
    for (int s = tid; s < S; s += nthr) {
        const uint4* base = (const uint4*)(sp + (size_t)s * CC);
        float4 su = {0.f, 0.f, 0.f, 0.f};
        #pragma unroll
        for (int g = 0; g < 2; ++g) {
            uint4 q0 = base[g * 4 + 0], q1 = base[g * 4 + 1];
            uint4 q2 = base[g * 4 + 2], q3 = base[g * 4 + 3];
            unsigned int uu[16] = {q0.x, q0.y, q0.z, q0.w, q1.x, q1.y, q1.z, q1.w,
                                   q2.x, q2.y, q2.z, q2.w, q3.x, q3.y, q3.z, q3.w};
            ushort4 t[16];
            #pragma unroll
            for (int c = 0; c < 16; ++c) t[c] = em4[uu[c] & 0xFFFFu];  // 16 loads in flight
            #pragma unroll
            for (int c = 0; c < 16; ++c) {
                float w = bf2f((unsigned short)(uu[c] >> 16));
                su.x = fmaf(bf2f(t[c].x), w, su.x);
                su.y = fmaf(bf2f(t[c].y), w, su.y);
                su.z = fmaf(bf2f(t[c].z), w, su.z);
                su.w = fmaf(bf2f(t[c].w), w, su.w);
            }
        }
        ushort4 o;
        o.x = f2bf(su.x); o.y = f2bf(su.y);
        o.z = f2bf(su.z); o.w = f2bf(su.w);
        nm4[s] = o;
    }
    __syncthreads();
}

template <typename NMP>
static __device__ __forceinline__ void do_root(NMP nm4, const ushort4* __restrict__ rpk,
                                               float* __restrict__ out, int b0, int tid) {
    if (tid < 4) {
        int col = tid;
        float su = 0.f;
        #pragma unroll
        for (int c = 0; c < CC; ++c) {
            ushort4 r = rpk[c];
            ushort4 a = nm4[r.x];
            ushort4 b = nm4[r.y];
            const unsigned short* ap = &a.x;
            const unsigned short* bp = &b.x;
            su = fmaf(bf2f(ap[col]) * bf2f(bp[col]), bf2f(r.z), su);
        }
        out[b0 + col] = (flog2(su) - ROOT_LOG2_SCALE) * LN2;
    }
}

// ---------------------------------------------------------------------------
// mega A: block owns 4 batch cols; nm AND em slices in LDS (135 KB, dynamic
// opt-in). 1024 threads. Whole net, __syncthreads-only between phases.
// ---------------------------------------------------------------------------
__global__ void __launch_bounds__(1024, 1) k_mega_lds(
        const int* __restrict__ x, const unsigned short* __restrict__ lpT,
        const unsigned int* __restrict__ ppk, const unsigned int* __restrict__ spk,
        const ushort4* __restrict__ rpk, float* __restrict__ out) {
    extern __shared__ ushort4 smem4[];
    ushort4* nm4 = smem4;                 // [8192] = 64 KB
    ushort4* em4 = smem4 + 8192;          // [8192] = 64 KB
    int* xv = (int*)(smem4 + 16384);      // [4][256] = 4 KB
    int tid = threadIdx.x;
    int b0 = blockIdx.x * 4;

    if (tid < 1024) {
        int c = tid >> 8, v = tid & 255;
        xv[tid] = x[(b0 + c) * VV + v];
    }
    __syncthreads();
    for (int i = tid; i < N0; i += 1024) {   // input gather via transposed lpT
        int v = i >> 5;
        ushort4 o;
        o.x = lpT[(size_t)xv[v]       * N0 + i];
        o.y = lpT[(size_t)xv[256 + v] * N0 + i];
        o.z = lpT[(size_t)xv[512 + v] * N0 + i];
        o.w = lpT[(size_t)xv[768 + v] * N0 + i];
        nm4[i] = o;
    }
    __syncthreads();
    do_layer(nm4, em4, ppk,         spk,          8192, 4096, tid, 1024);
    do_layer(nm4, em4, ppk + 8192,  spk + 131072, 4096, 2048, tid, 1024);
    do_layer(nm4, em4, ppk + 12288, spk + 196608, 2048, 1024, tid, 1024);
    do_root(nm4, rpk, out, b0, tid);
}

// ---------------------------------------------------------------------------
// mega B (fallback if >64KB LDS opt-in fails): em in LDS (64 KB), nm in a
// per-block global slice.
// ---------------------------------------------------------------------------
__global__ void __launch_bounds__(1024, 1) k_mega_glb(
        const int* __restrict__ x, const unsigned short* __restrict__ lpT,
        const unsigned int* __restrict__ ppk, const unsigned int* __restrict__ spk,
        const ushort4* __restrict__ rpk, ushort4* __restrict__ nmg,
        float* __restrict__ out) {
    extern __shared__ ushort4 smem4[];
    ushort4* em4 = smem4;                              // [8192] = 64 KB
    ushort4* nm4 = nmg + (size_t)blockIdx.x * 8192;    // global slice
    int tid = threadIdx.x;
    int b0 = blockIdx.x * 4;

    for (int i = tid; i < N0; i += 1024) {
        int v = i >> 5;
        int x0 = x[(b0 + 0) * VV + v], x1 = x[(b0 + 1) * VV + v];
        int x2 = x[(b0 + 2) * VV + v], x3 = x[(b0 + 3) * VV + v];
        ushort4 o;
        o.x = lpT[(size_t)x0 * N0 + i];
        o.y = lpT[(size_t)x1 * N0 + i];
        o.z = lpT[(size_t)x2 * N0 + i];
        o.w = lpT[(size_t)x3 * N0 + i];
        nm4[i] = o;
    }
    __syncthreads();
    do_layer(nm4, em4, ppk,         spk,          8192, 4096, tid, 1024);
    do_layer(nm4, em4, ppk + 8192,  spk + 131072, 4096, 2048, tid, 1024);
    do_layer(nm4, em4, ppk + 12288, spk + 196608, 2048, 1024, tid, 1024);
    do_root(nm4, rpk, out, b0, tid);
}

// ---------------------------------------------------------------------------
// Launch: 2 dispatches (prep + mega). Deterministic A/B pick by whether the
// 135 KB dynamic-LDS opt-in succeeds.
// ---------------------------------------------------------------------------
extern "C" void kernel_launch(void* const* d_in, const int* in_sizes, int n_in,
                              void* d_out, int out_size, void* d_ws, size_t ws_size,
                              hipStream_t stream) {
    const int*   x         = (const int*)  d_in[0];
    const float* in_logits = (const float*)d_in[1];
    const float* w1        = (const float*)d_in[2];
    const float* w2        = (const float*)d_in[3];
    const float* w3        = (const float*)d_in[4];
    const float* w4        = (const float*)d_in[5];
    const int*   pids1     = (const int*)  d_in[6];
    const int*   pids2     = (const int*)  d_in[7];
    const int*   pids3     = (const int*)  d_in[8];
    const int*   pids4     = (const int*)  d_in[9];
    const int*   cids1     = (const int*)  d_in[10];
    const int*   cids2     = (const int*)  d_in[11];
    const int*   cids3     = (const int*)  d_in[12];
    const int*   cids4     = (const int*)  d_in[13];
    float* out = (float*)d_out;

    char* ws = (char*)d_ws;
    unsigned short* lpT = (unsigned short*)ws;                    // 64*8192 bf16 = 1 MB
    unsigned int*   ppk = (unsigned int*)(ws + 1048576);          // 14336 u32
    unsigned int*   spk = (unsigned int*)(ws + 1105920);          // 229376 u32
    ushort4*        rpk = (ushort4*)(ws + 2023424);               // 32 x 8 B
    ushort4*        nmg = (ushort4*)(ws + 2023936);               // 256*8192*8 B = 16 MB (B only)

    k_prep<<<3001, 256, 0, stream>>>(in_logits, w1, w2, w3, w4,
                                     cids1, cids2, cids3, cids4,
                                     pids1, pids2, pids3, pids4,
                                     lpT, ppk, spk, rpk);

    const int SMEM_A = 135168;  // 64K nm + 64K em + 4K xv
    const int SMEM_B = 65536;   // 64K em
    hipError_t e = hipFuncSetAttribute((const void*)k_mega_lds,
                                       hipFuncAttributeMaxDynamicSharedMemorySize, SMEM_A);
    if (e == hipSuccess) {
        k_mega_lds<<<256, 1024, SMEM_A, stream>>>(x, lpT, ppk, spk, rpk, out);
    } else {
        (void)hipGetLastError();  // clear sticky error from failed opt-in
        hipFuncSetAttribute((const void*)k_mega_glb,
                            hipFuncAttributeMaxDynamicSharedMemorySize, SMEM_B);
        k_mega_glb<<<256, 1024, SMEM_B, stream>>>(x, lpT, ppk, spk, rpk, nmg, out);
    }
}

// Round 14
// 124.346 us; speedup vs baseline: 9.6036x; 1.0127x over previous
//
#include <hip/hip_runtime.h>
#include <math.h>

#define BB 1024   // batch
#define VV 256    // variables
#define KK 64     // categories
#define N0 8192   // input nodes
#define CC 32     // sum-node children

#define LOG2E 1.4426950408889634f
#define LN2   0.6931471805599453f
// layer-1 weight scale 2^13 centers linear-domain values near 2^0;
// accumulated scale at the root su is 2^(8*13) = 2^104.
#define W1SCALE 8192.0f
#define ROOT_LOG2_SCALE 104.0f

static __device__ __forceinline__ float flog2(float x) { return __builtin_amdgcn_logf(x); }
static __device__ __forceinline__ float bf2f(unsigned short u) {
    union { unsigned int i; float f; } c; c.i = (unsigned int)u << 16; return c.f;
}
static __device__ __forceinline__ unsigned short f2bf(float f) {
    union { float f; unsigned int i; } c; c.f = f;
    unsigned int r = c.i + 0x7FFFu + ((c.i >> 16) & 1u);  // RNE
    return (unsigned short)(r >> 16);
}

// ---------------------------------------------------------------------------
// prep (linear domain, BYTE-OFFSET indices: all local ids *8, fits u16):
//  bid <  2048 : lpT[k][i] = softmax(in_logits[i])[k]      (bf16, TRANSPOSED)
//  bid <  2944 : spk[n][c] = (cid*8) | (bf16 lin-weight <<16); layer1 w *= 2^13
//  bid <  3000 : ppk[e]    = (p0*8) | ((p1*8) << 16)
//  bid == 3000 : rpk[c]    = {p0*8, p1*8, bf16 softmax(w4), 0}
// ---------------------------------------------------------------------------
__global__ void __launch_bounds__(256) k_prep(
        const float* __restrict__ logits,
        const float* __restrict__ w1, const float* __restrict__ w2,
        const float* __restrict__ w3, const float* __restrict__ w4,
        const int* __restrict__ cids1, const int* __restrict__ cids2,
        const int* __restrict__ cids3, const int* __restrict__ cids4,
        const int* __restrict__ pids1, const int* __restrict__ pids2,
        const int* __restrict__ pids3, const int* __restrict__ pids4,
        unsigned short* __restrict__ lpT, unsigned int* __restrict__ ppk,
        unsigned int* __restrict__ spk, ushort4* __restrict__ rpk) {
    int bid = blockIdx.x, tid = threadIdx.x;
    __shared__ unsigned short tile[4][64];
    if (bid < 2048) {
        int i = bid * 4 + (tid >> 6);
        int k = tid & 63;
        float l = logits[(size_t)i * KK + k];
        float m = l;
        #pragma unroll
        for (int d = 32; d; d >>= 1) m = fmaxf(m, __shfl_xor(m, d));
        float e = __expf(l - m);
        float s = e;
        #pragma unroll
        for (int d = 32; d; d >>= 1) s += __shfl_xor(s, d);
        tile[tid >> 6][k] = f2bf(e / s);          // linear softmax prob
        __syncthreads();
        if (tid < 64) {  // transposed store: 4 consecutive i per k
            ushort4 o;
            o.x = tile[0][tid]; o.y = tile[1][tid];
            o.z = tile[2][tid]; o.w = tile[3][tid];
            *(ushort4*)(lpT + (size_t)tid * N0 + bid * 4) = o;
        }
    } else if (bid < 2944) {
        int n = (bid - 2048) * 8 + (tid >> 5);
        int lane = tid & 31;
        if (n < 7168) {
            const float* wsrc; const int* csrc; float scale;
            if (n < 4096)      { wsrc = w1 + (size_t)n * CC;          csrc = cids1 + (size_t)n * CC;          scale = W1SCALE; }
            else if (n < 6144) { wsrc = w2 + (size_t)(n - 4096) * CC; csrc = cids2 + (size_t)(n - 4096) * CC; scale = 1.0f; }
            else               { wsrc = w3 + (size_t)(n - 6144) * CC; csrc = cids3 + (size_t)(n - 6144) * CC; scale = 1.0f; }
            float lw = wsrc[lane];
            float m = lw;
            #pragma unroll
            for (int d = 16; d; d >>= 1) m = fmaxf(m, __shfl_xor(m, d, 32));
            float e = __expf(lw - m);
            float s = e;
            #pragma unroll
            for (int d = 16; d; d >>= 1) s += __shfl_xor(s, d, 32);
            unsigned int cid8 = (unsigned int)(csrc[lane] - 1) * 8u;
            spk[(size_t)n * CC + lane] = cid8 | ((unsigned int)f2bf(e / s * scale) << 16);
        }
    } else if (bid < 3000) {
        int idx = (bid - 2944) * 256 + tid;  // 14336 elements total
        int p0, p1;
        if (idx < 8192)       { p0 = pids1[idx * 2] - 1;                p1 = pids1[idx * 2 + 1] - 1; }
        else if (idx < 12288) { int e = idx - 8192;  p0 = pids2[e * 2] - 8193;  p1 = pids2[e * 2 + 1] - 8193; }
        else                  { int e = idx - 12288; p0 = pids3[e * 2] - 12289; p1 = pids3[e * 2 + 1] - 12289; }
        ppk[idx] = ((unsigned int)p0 * 8u) | (((unsigned int)p1 * 8u) << 16);
    } else {
        if (tid < CC) {
            float lw = w4[tid];
            float m = lw;
            #pragma unroll
            for (int d = 16; d; d >>= 1) m = fmaxf(m, __shfl_xor(m, d, 32));
            float e = __expf(lw - m);
            float s = e;
            #pragma unroll
            for (int d = 16; d; d >>= 1) s += __shfl_xor(s, d, 32);
            int el = cids4[tid] - 1;
            ushort4 r;
            r.x = (unsigned short)((pids4[el * 2]     - 14337) * 8);
            r.y = (unsigned short)((pids4[el * 2 + 1] - 14337) * 8);
            r.z = f2bf(e / s); r.w = 0;
            rpk[tid] = r;
        }
    }
}

// ---------------------------------------------------------------------------
// One layer for a 4-column slice, linear domain, fully load-batched.
// prod: em[e] = nm[p0]*nm[p1], 4 elements batched (8 loads in flight).
// sum: per node, ALL 32 ds_read_b64 issued back-to-back (one waitcnt), then
// 128 FMAs. Indices are byte offsets (pre-scaled *8 in prep).
// ---------------------------------------------------------------------------
template <typename NMP>
static __device__ __forceinline__ void do_layer(
        NMP nm4, ushort4* em4,
        const unsigned int* __restrict__ pp, const unsigned int* __restrict__ sp,
        int E, int S, int tid, int nthr) {
    const char* nmB = (const char*)nm4;
    const char* emB = (const char*)em4;
    for (int e = tid; e < E; e += nthr * 4) {
        unsigned int pw[4];
        ushort4 av[4], bv[4];
        int cnt = 0;
        #pragma unroll
        for (int j = 0; j < 4; ++j) {
            int ee = e + j * nthr;
            if (ee < E) { pw[j] = pp[ee]; ++cnt; }
        }
        #pragma unroll
        for (int j = 0; j < 4; ++j) {
            if (j < cnt) {
                av[j] = *(const ushort4*)(nmB + (pw[j] & 0xFFFFu));
                bv[j] = *(const ushort4*)(nmB + (pw[j] >> 16));
            }
        }
        #pragma unroll
        for (int j = 0; j < 4; ++j) {
            if (j < cnt) {
                ushort4 o;
                o.x = f2bf(bf2f(av[j].x) * bf2f(bv[j].x));
                o.y = f2bf(bf2f(av[j].y) * bf2f(bv[j].y));
                o.z = f2bf(bf2f(av[j].z) * bf2f(bv[j].z));
                o.w = f2bf(bf2f(av[j].w) * bf2f(bv[j].w));
                em4[e + j * nthr] = o;
            }
        }
    }
    __syncthreads();
    for (int s = tid; s < S; s += nthr) {
        const uint4* base = (const uint4*)(sp + (size_t)s * CC);
        uint4 q[8];
        #pragma unroll
        for (int j = 0; j < 8; ++j) q[j] = base[j];
        unsigned int uu[32];
        #pragma unroll
        for (int j = 0; j < 8; ++j) {
            uu[j * 4 + 0] = q[j].x; uu[j * 4 + 1] = q[j].y;
            uu[j * 4 + 2] = q[j].z; uu[j * 4 + 3] = q[j].w;
        }
        ushort4 t[32];
        #pragma unroll
        for (int c = 0; c < 32; ++c) t[c] = *(const ushort4*)(emB + (uu[c] & 0xFFFFu));
        float4 su = {0.f, 0.f, 0.f, 0.f};
        #pragma unroll
        for (int c = 0; c < 32; ++c) {
            float w = bf2f((unsigned short)(uu[c] >> 16));
            su.x = fmaf(bf2f(t[c].x), w, su.x);
            su.y = fmaf(bf2f(t[c].y), w, su.y);
            su.z = fmaf(bf2f(t[c].z), w, su.z);
            su.w = fmaf(bf2f(t[c].w), w, su.w);
        }
        ushort4 o;
        o.x = f2bf(su.x); o.y = f2bf(su.y);
        o.z = f2bf(su.z); o.w = f2bf(su.w);
        nm4[s] = o;
    }
    __syncthreads();
}

template <typename NMP>
static __device__ __forceinline__ void do_root(NMP nm4, const ushort4* __restrict__ rpk,
                                               float* __restrict__ out, int b0, int tid) {
    const char* nmB = (const char*)nm4;
    if (tid < 4) {
        int col = tid;
        float su = 0.f;
        #pragma unroll
        for (int c = 0; c < CC; ++c) {
            ushort4 r = rpk[c];
            ushort4 a = *(const ushort4*)(nmB + r.x);
            ushort4 b = *(const ushort4*)(nmB + r.y);
            const unsigned short* ap = &a.x;
            const unsigned short* bp = &b.x;
            su = fmaf(bf2f(ap[col]) * bf2f(bp[col]), bf2f(r.z), su);
        }
        out[b0 + col] = (flog2(su) - ROOT_LOG2_SCALE) * LN2;
    }
}

// ---------------------------------------------------------------------------
// mega A: block owns 4 batch cols; nm AND em slices in LDS (135 KB, dynamic
// opt-in). 1024 threads. Whole net, __syncthreads-only between phases.
// ---------------------------------------------------------------------------
__global__ void __launch_bounds__(1024, 1) k_mega_lds(
        const int* __restrict__ x, const unsigned short* __restrict__ lpT,
        const unsigned int* __restrict__ ppk, const unsigned int* __restrict__ spk,
        const ushort4* __restrict__ rpk, float* __restrict__ out) {
    extern __shared__ ushort4 smem4[];
    ushort4* nm4 = smem4;                 // [8192] = 64 KB
    ushort4* em4 = smem4 + 8192;          // [8192] = 64 KB
    int* xv = (int*)(smem4 + 16384);      // [4][256] = 4 KB
    int tid = threadIdx.x;
    int b0 = blockIdx.x * 4;

    {
        int c = tid >> 8, v = tid & 255;
        xv[tid] = x[(b0 + c) * VV + v];
    }
    __syncthreads();
    for (int i = tid; i < N0; i += 1024) {   // input gather via transposed lpT
        int v = i >> 5;
        ushort4 o;
        o.x = lpT[(size_t)xv[v]       * N0 + i];
        o.y = lpT[(size_t)xv[256 + v] * N0 + i];
        o.z = lpT[(size_t)xv[512 + v] * N0 + i];
        o.w = lpT[(size_t)xv[768 + v] * N0 + i];
        nm4[i] = o;
    }
    __syncthreads();
    do_layer(nm4, em4, ppk,         spk,          8192, 4096, tid, 1024);
    do_layer(nm4, em4, ppk + 8192,  spk + 131072, 4096, 2048, tid, 1024);
    do_layer(nm4, em4, ppk + 12288, spk + 196608, 2048, 1024, tid, 1024);
    do_root(nm4, rpk, out, b0, tid);
}

// ---------------------------------------------------------------------------
// mega B (fallback if >64KB LDS opt-in fails): em in LDS (64 KB), nm in a
// per-block global slice.
// ---------------------------------------------------------------------------
__global__ void __launch_bounds__(1024, 1) k_mega_glb(
        const int* __restrict__ x, const unsigned short* __restrict__ lpT,
        const unsigned int* __restrict__ ppk, const unsigned int* __restrict__ spk,
        const ushort4* __restrict__ rpk, ushort4* __restrict__ nmg,
        float* __restrict__ out) {
    extern __shared__ ushort4 smem4[];
    ushort4* em4 = smem4;                              // [8192] = 64 KB
    ushort4* nm4 = nmg + (size_t)blockIdx.x * 8192;    // global slice
    int tid = threadIdx.x;
    int b0 = blockIdx.x * 4;

    for (int i = tid; i < N0; i += 1024) {
        int v = i >> 5;
        int x0 = x[(b0 + 0) * VV + v], x1 = x[(b0 + 1) * VV + v];
        int x2 = x[(b0 + 2) * VV + v], x3 = x[(b0 + 3) * VV + v];
        ushort4 o;
        o.x = lpT[(size_t)x0 * N0 + i];
        o.y = lpT[(size_t)x1 * N0 + i];
        o.z = lpT[(size_t)x2 * N0 + i];
        o.w = lpT[(size_t)x3 * N0 + i];
        nm4[i] = o;
    }
    __syncthreads();
    do_layer(nm4, em4, ppk,         spk,          8192, 4096, tid, 1024);
    do_layer(nm4, em4, ppk + 8192,  spk + 131072, 4096, 2048, tid, 1024);
    do_layer(nm4, em4, ppk + 12288, spk + 196608, 2048, 1024, tid, 1024);
    do_root(nm4, rpk, out, b0, tid);
}

// ---------------------------------------------------------------------------
// Launch: 2 dispatches (prep + mega). Deterministic A/B pick by whether the
// 135 KB dynamic-LDS opt-in succeeds.
// ---------------------------------------------------------------------------
extern "C" void kernel_launch(void* const* d_in, const int* in_sizes, int n_in,
                              void* d_out, int out_size, void* d_ws, size_t ws_size,
                              hipStream_t stream) {
    const int*   x         = (const int*)  d_in[0];
    const float* in_logits = (const float*)d_in[1];
    const float* w1        = (const float*)d_in[2];
    const float* w2        = (const float*)d_in[3];
    const float* w3        = (const float*)d_in[4];
    const float* w4        = (const float*)d_in[5];
    const int*   pids1     = (const int*)  d_in[6];
    const int*   pids2     = (const int*)  d_in[7];
    const int*   pids3     = (const int*)  d_in[8];
    const int*   pids4     = (const int*)  d_in[9];
    const int*   cids1     = (const int*)  d_in[10];
    const int*   cids2     = (const int*)  d_in[11];
    const int*   cids3     = (const int*)  d_in[12];
    const int*   cids4     = (const int*)  d_in[13];
    float* out = (float*)d_out;

    char* ws = (char*)d_ws;
    unsigned short* lpT = (unsigned short*)ws;                    // 64*8192 bf16 = 1 MB
    unsigned int*   ppk = (unsigned int*)(ws + 1048576);          // 14336 u32
    unsigned int*   spk = (unsigned int*)(ws + 1105920);          // 229376 u32
    ushort4*        rpk = (ushort4*)(ws + 2023424);               // 32 x 8 B
    ushort4*        nmg = (ushort4*)(ws + 2023936);               // 256*8192*8 B = 16 MB (B only)

    k_prep<<<3001, 256, 0, stream>>>(in_logits, w1, w2, w3, w4,
                                     cids1, cids2, cids3, cids4,
                                     pids1, pids2, pids3, pids4,
                                     lpT, ppk, spk, rpk);

    const int SMEM_A = 135168;  // 64K nm + 64K em + 4K xv
    const int SMEM_B = 65536;   // 64K em
    hipError_t e = hipFuncSetAttribute((const void*)k_mega_lds,
                                       hipFuncAttributeMaxDynamicSharedMemorySize, SMEM_A);
    if (e == hipSuccess) {
        k_mega_lds<<<256, 1024, SMEM_A, stream>>>(x, lpT, ppk, spk, rpk, out);
    } else {
        (void)hipGetLastError();  // clear sticky error from failed opt-in
        hipFuncSetAttribute((const void*)k_mega_glb,
                            hipFuncAttributeMaxDynamicSharedMemorySize, SMEM_B);
        k_mega_glb<<<256, 1024, SMEM_B, stream>>>(x, lpT, ppk, spk, rpk, nmg, out);
    }
}